// Round 1
// baseline (8842.518 us; speedup 1.0000x reference)
//
#include <hip/hip_runtime.h>
#include <math.h>

#define BQ 4096
#define NMEM 32768
#define DD 512
#define TOPN 10
#define NSLICE 8
#define SLICE_COLS (NMEM / NSLICE)   /* 4096 */
#define FINF 3.402823466e+38f

// ---------------- top-k helpers (register-resident, unrolled) ----------------
__device__ __forceinline__ bool lt_si(float s, int j, float s2, int j2) {
    return (s < s2) || (s == s2 && j < j2);   // lexicographic: matches top_k tie-break
}

__device__ __forceinline__ void topk_insert(float (&ts)[TOPN], int (&ti)[TOPN], float s, int j) {
    if (!lt_si(s, j, ts[TOPN-1], ti[TOPN-1])) return;
    #pragma unroll
    for (int p = TOPN-1; p > 0; --p) {
        if (lt_si(s, j, ts[p-1], ti[p-1])) { ts[p] = ts[p-1]; ti[p] = ti[p-1]; }
        else { ts[p] = s; ti[p] = j; return; }
    }
    ts[0] = s; ti[0] = j;
}

// ---------------- ||M_j||^2 ----------------
__global__ __launch_bounds__(256) void mnorm_kernel(const float* __restrict__ M,
                                                    float* __restrict__ mnorm) {
    int row = blockIdx.x * 4 + (threadIdx.x >> 6);
    int lane = threadIdx.x & 63;
    const float* mr = M + (size_t)row * DD;
    float s = 0.f;
    #pragma unroll
    for (int k = 0; k < DD; k += 64) { float v = mr[k + lane]; s = fmaf(v, v, s); }
    #pragma unroll
    for (int off = 32; off; off >>= 1) s += __shfl_xor(s, off, 64);
    if (lane == 0) mnorm[row] = s;
}

// ---------------- fused distance GEMM + per-slice top-10 ----------------
// grid: (128 row-tiles, 8 slices). block 256 = 16 row-threads x 16 col-threads.
// thread (rt, ct) owns rows {2rt, 2rt+1} and cols {4ct..4ct+3} of each 64-col tile.
__global__ __launch_bounds__(256) void knn_kernel(
        const float* __restrict__ Q, const float* __restrict__ Mm,
        const float* __restrict__ mnorm,
        float* __restrict__ slice_s, int* __restrict__ slice_i) {
    __shared__ union {
        struct { float As[64][34]; float Bs[64][68]; } t;   // 26.1 KB
        struct { float ms[32][16][TOPN]; int mi[32][16][TOPN]; } m; // 40 KB
    } sh;
    const int tid = threadIdx.x;
    const int rt = tid >> 4;
    const int ct = tid & 15;
    const int m0 = blockIdx.x * 32;
    const int c0 = blockIdx.y * SLICE_COLS;

    float ts0[TOPN], ts1[TOPN]; int ti0[TOPN], ti1[TOPN];
    #pragma unroll
    for (int p = 0; p < TOPN; ++p) {
        ts0[p] = FINF; ts1[p] = FINF; ti0[p] = 0x7fffffff; ti1[p] = 0x7fffffff;
    }

    for (int t = 0; t < SLICE_COLS / 64; ++t) {
        float4 acc0 = make_float4(0.f,0.f,0.f,0.f);
        float4 acc1 = make_float4(0.f,0.f,0.f,0.f);
        for (int kt = 0; kt < DD; kt += 64) {
            __syncthreads();
            #pragma unroll
            for (int i = 0; i < 2; ++i) {       // A: 32 rows x 64 k
                int fl = tid + i * 256;
                int row = fl >> 4;
                int kc = (fl & 15) << 2;
                float4 v = *(const float4*)(Q + (size_t)(m0 + row) * DD + kt + kc);
                sh.t.As[kc+0][row] = v.x; sh.t.As[kc+1][row] = v.y;
                sh.t.As[kc+2][row] = v.z; sh.t.As[kc+3][row] = v.w;
            }
            #pragma unroll
            for (int i = 0; i < 4; ++i) {       // B: 64 cols x 64 k
                int fl = tid + i * 256;
                int row = fl >> 4;
                int kc = (fl & 15) << 2;
                float4 v = *(const float4*)(Mm + (size_t)(c0 + t*64 + row) * DD + kt + kc);
                sh.t.Bs[kc+0][row] = v.x; sh.t.Bs[kc+1][row] = v.y;
                sh.t.Bs[kc+2][row] = v.z; sh.t.Bs[kc+3][row] = v.w;
            }
            __syncthreads();
            #pragma unroll
            for (int k = 0; k < 64; ++k) {
                float2 a = *(const float2*)&sh.t.As[k][rt << 1];
                float4 b = *(const float4*)&sh.t.Bs[k][ct << 2];
                acc0.x = fmaf(a.x, b.x, acc0.x); acc0.y = fmaf(a.x, b.y, acc0.y);
                acc0.z = fmaf(a.x, b.z, acc0.z); acc0.w = fmaf(a.x, b.w, acc0.w);
                acc1.x = fmaf(a.y, b.x, acc1.x); acc1.y = fmaf(a.y, b.y, acc1.y);
                acc1.z = fmaf(a.y, b.z, acc1.z); acc1.w = fmaf(a.y, b.w, acc1.w);
            }
        }
        int jb = c0 + t*64 + (ct << 2);
        float4 mn = *(const float4*)(mnorm + jb);
        topk_insert(ts0, ti0, fmaf(-2.f, acc0.x, mn.x), jb+0);
        topk_insert(ts0, ti0, fmaf(-2.f, acc0.y, mn.y), jb+1);
        topk_insert(ts0, ti0, fmaf(-2.f, acc0.z, mn.z), jb+2);
        topk_insert(ts0, ti0, fmaf(-2.f, acc0.w, mn.w), jb+3);
        topk_insert(ts1, ti1, fmaf(-2.f, acc1.x, mn.x), jb+0);
        topk_insert(ts1, ti1, fmaf(-2.f, acc1.y, mn.y), jb+1);
        topk_insert(ts1, ti1, fmaf(-2.f, acc1.z, mn.z), jb+2);
        topk_insert(ts1, ti1, fmaf(-2.f, acc1.w, mn.w), jb+3);
    }
    __syncthreads();
    #pragma unroll
    for (int p = 0; p < TOPN; ++p) {
        sh.m.ms[(rt<<1)+0][ct][p] = ts0[p]; sh.m.mi[(rt<<1)+0][ct][p] = ti0[p];
        sh.m.ms[(rt<<1)+1][ct][p] = ts1[p]; sh.m.mi[(rt<<1)+1][ct][p] = ti1[p];
    }
    __syncthreads();
    if (tid < 32) {
        float fs[TOPN]; int fi[TOPN];
        #pragma unroll
        for (int p = 0; p < TOPN; ++p) { fs[p] = FINF; fi[p] = 0x7fffffff; }
        for (int c = 0; c < 16; ++c) {
            #pragma unroll
            for (int p = 0; p < TOPN; ++p)
                topk_insert(fs, fi, sh.m.ms[tid][c][p], sh.m.mi[tid][c][p]);
        }
        size_t base = ((size_t)(m0 + tid) * NSLICE + blockIdx.y) * TOPN;
        #pragma unroll
        for (int p = 0; p < TOPN; ++p) { slice_s[base+p] = fs[p]; slice_i[base+p] = fi[p]; }
    }
}

// ---------------- cross-slice merge ----------------
__global__ __launch_bounds__(256) void knn_merge_kernel(
        const float* __restrict__ slice_s, const int* __restrict__ slice_i,
        int* __restrict__ knn_idx) {
    const int row = blockIdx.x * 256 + threadIdx.x;
    float ts[TOPN]; int ti[TOPN];
    #pragma unroll
    for (int p = 0; p < TOPN; ++p) { ts[p] = FINF; ti[p] = 0x7fffffff; }
    for (int s = 0; s < NSLICE; ++s) {
        size_t base = ((size_t)row * NSLICE + s) * TOPN;
        #pragma unroll
        for (int p = 0; p < TOPN; ++p) topk_insert(ts, ti, slice_s[base+p], slice_i[base+p]);
    }
    #pragma unroll
    for (int p = 0; p < TOPN; ++p) knn_idx[row * TOPN + p] = ti[p];
}

// ---------------- generic fp32 GEMM: C[M,512] = A[M,512] @ Bw[512,512]^T + bias ----------------
// grid (N/64=8, M/64); block 256; 64x64 tile, 4x4 micro, K-tile 16.
template<int ACT>   // 0 = none, 1 = leaky_relu(0.01)
__global__ __launch_bounds__(256) void gemm_nt_kernel(
        const float* __restrict__ A, const float* __restrict__ Bw,
        const float* __restrict__ bias, float* __restrict__ C) {
    __shared__ float As[16][68];
    __shared__ float Bs[16][68];
    const int tid = threadIdx.x;
    const int tr = tid >> 4, tc = tid & 15;
    const int m0 = blockIdx.y << 6;
    const int n0 = blockIdx.x << 6;
    const int lrow = tid >> 2;
    const int lkc  = (tid & 3) << 2;
    float acc[4][4] = {};
    for (int kt = 0; kt < DD; kt += 16) {
        __syncthreads();
        {
            float4 va = *(const float4*)(A  + (size_t)(m0 + lrow) * DD + kt + lkc);
            As[lkc+0][lrow] = va.x; As[lkc+1][lrow] = va.y;
            As[lkc+2][lrow] = va.z; As[lkc+3][lrow] = va.w;
            float4 vb = *(const float4*)(Bw + (size_t)(n0 + lrow) * DD + kt + lkc);
            Bs[lkc+0][lrow] = vb.x; Bs[lkc+1][lrow] = vb.y;
            Bs[lkc+2][lrow] = vb.z; Bs[lkc+3][lrow] = vb.w;
        }
        __syncthreads();
        #pragma unroll
        for (int k = 0; k < 16; ++k) {
            float4 a = *(const float4*)&As[k][tr << 2];
            float4 b = *(const float4*)&Bs[k][tc << 2];
            acc[0][0]=fmaf(a.x,b.x,acc[0][0]); acc[0][1]=fmaf(a.x,b.y,acc[0][1]);
            acc[0][2]=fmaf(a.x,b.z,acc[0][2]); acc[0][3]=fmaf(a.x,b.w,acc[0][3]);
            acc[1][0]=fmaf(a.y,b.x,acc[1][0]); acc[1][1]=fmaf(a.y,b.y,acc[1][1]);
            acc[1][2]=fmaf(a.y,b.z,acc[1][2]); acc[1][3]=fmaf(a.y,b.w,acc[1][3]);
            acc[2][0]=fmaf(a.z,b.x,acc[2][0]); acc[2][1]=fmaf(a.z,b.y,acc[2][1]);
            acc[2][2]=fmaf(a.z,b.z,acc[2][2]); acc[2][3]=fmaf(a.z,b.w,acc[2][3]);
            acc[3][0]=fmaf(a.w,b.x,acc[3][0]); acc[3][1]=fmaf(a.w,b.y,acc[3][1]);
            acc[3][2]=fmaf(a.w,b.z,acc[3][2]); acc[3][3]=fmaf(a.w,b.w,acc[3][3]);
        }
    }
    float4 bv = *(const float4*)(bias + n0 + (tc << 2));
    #pragma unroll
    for (int i = 0; i < 4; ++i) {
        float4 o;
        o.x = acc[i][0] + bv.x; o.y = acc[i][1] + bv.y;
        o.z = acc[i][2] + bv.z; o.w = acc[i][3] + bv.w;
        if (ACT == 1) {
            o.x = o.x >= 0.f ? o.x : 0.01f * o.x;
            o.y = o.y >= 0.f ? o.y : 0.01f * o.y;
            o.z = o.z >= 0.f ? o.z : 0.01f * o.z;
            o.w = o.w >= 0.f ? o.w : 0.01f * o.w;
        }
        *(float4*)(C + (size_t)(m0 + (tr << 2) + i) * DD + n0 + (tc << 2)) = o;
    }
}

// ---------------- attention: one block per query row, one wave per head ----------------
__global__ __launch_bounds__(512) void attn_kernel(
        const float* __restrict__ qh, const float* __restrict__ Kall,
        const float* __restrict__ Vall, const int* __restrict__ knn_idx,
        float* __restrict__ ctx) {
    const int b = blockIdx.x;
    const int h = threadIdx.x >> 6;
    const int l = threadIdx.x & 63;
    const int col = (h << 6) + l;
    int idxs[TOPN];
    #pragma unroll
    for (int n = 0; n < TOPN; ++n) idxs[n] = knn_idx[b * TOPN + n];
    const float q = qh[(size_t)b * DD + col];
    float sc[TOPN];
    #pragma unroll
    for (int n = 0; n < TOPN; ++n) {
        float p = q * Kall[(size_t)idxs[n] * DD + col];
        #pragma unroll
        for (int off = 32; off; off >>= 1) p += __shfl_xor(p, off, 64);
        sc[n] = p * 0.125f;   // 1/sqrt(64)
    }
    float mx = sc[0];
    #pragma unroll
    for (int n = 1; n < TOPN; ++n) mx = fmaxf(mx, sc[n]);
    float se = 0.f;
    #pragma unroll
    for (int n = 0; n < TOPN; ++n) { sc[n] = expf(sc[n] - mx); se += sc[n]; }
    const float inv = 1.f / se;
    float o = 0.f;
    #pragma unroll
    for (int n = 0; n < TOPN; ++n)
        o = fmaf(sc[n] * inv, Vall[(size_t)idxs[n] * DD + col], o);
    ctx[(size_t)b * DD + col] = o;
}

// ---------------- residual add + layernorm ----------------
__global__ __launch_bounds__(256) void add_ln_kernel(
        const float* __restrict__ X, const float* __restrict__ Y,
        const float* __restrict__ g, const float* __restrict__ be,
        float* __restrict__ out) {
    const int row = blockIdx.x;
    const int t = threadIdx.x;
    const size_t base = (size_t)row * DD;
    float v0 = X[base + t]       + Y[base + t];
    float v1 = X[base + 256 + t] + Y[base + 256 + t];
    float s = v0 + v1, sq = v0 * v0 + v1 * v1;
    #pragma unroll
    for (int off = 32; off; off >>= 1) { s += __shfl_xor(s, off, 64); sq += __shfl_xor(sq, off, 64); }
    __shared__ float rs[4], rq[4];
    const int w = t >> 6, l = t & 63;
    if (l == 0) { rs[w] = s; rq[w] = sq; }
    __syncthreads();
    float tot  = rs[0] + rs[1] + rs[2] + rs[3];
    float totq = rq[0] + rq[1] + rq[2] + rq[3];
    float mu = tot * (1.f / DD);
    float var = totq * (1.f / DD) - mu * mu;
    float rstd = rsqrtf(var + 1e-5f);
    out[base + t]       = (v0 - mu) * rstd * g[t]       + be[t];
    out[base + 256 + t] = (v1 - mu) * rstd * g[256 + t] + be[256 + t];
}

// ---------------- launch ----------------
extern "C" void kernel_launch(void* const* d_in, const int* in_sizes, int n_in,
                              void* d_out, int out_size, void* d_ws, size_t ws_size,
                              hipStream_t stream) {
    const float* visit = (const float*)d_in[0];
    const float* Epat  = (const float*)d_in[1];
    const float* Emed  = (const float*)d_in[2];
    const float* Wq = (const float*)d_in[3];
    const float* Wk = (const float*)d_in[4];
    const float* Wv = (const float*)d_in[5];
    const float* bq = (const float*)d_in[6];
    const float* bk = (const float*)d_in[7];
    const float* bv = (const float*)d_in[8];
    const float* Wo = (const float*)d_in[9];
    const float* bo = (const float*)d_in[10];
    const float* W1 = (const float*)d_in[11];
    const float* b1 = (const float*)d_in[12];
    const float* W2 = (const float*)d_in[13];
    const float* b2 = (const float*)d_in[14];
    const float* ln1g = (const float*)d_in[15];
    const float* ln1b = (const float*)d_in[16];
    const float* ln2g = (const float*)d_in[17];
    const float* ln2b = (const float*)d_in[18];
    float* out = (float*)d_out;

    float* w = (float*)d_ws;
    float* mnorm   = w;            w += NMEM;
    float* slice_s = w;            w += (size_t)BQ * NSLICE * TOPN;
    int*   slice_i = (int*)w;      w += (size_t)BQ * NSLICE * TOPN;
    int*   knn_idx = (int*)w;      w += (size_t)BQ * TOPN + 64;  // keep 256B-aligned
    float* qh      = w;            w += (size_t)BQ * DD;
    float* Kall    = w;            w += (size_t)NMEM * DD;
    float* Vall    = w;            w += (size_t)NMEM * DD;
    float* ctx     = w;            w += (size_t)BQ * DD;
    float* attn_o  = w;            w += (size_t)BQ * DD;
    float* x1      = w;            w += (size_t)BQ * DD;
    float* h1      = w;            w += (size_t)BQ * DD;
    float* ff      = w;            w += (size_t)BQ * DD;

    mnorm_kernel<<<NMEM / 4, 256, 0, stream>>>(Epat, mnorm);
    knn_kernel<<<dim3(BQ / 32, NSLICE), 256, 0, stream>>>(visit, Epat, mnorm, slice_s, slice_i);
    knn_merge_kernel<<<BQ / 256, 256, 0, stream>>>(slice_s, slice_i, knn_idx);

    gemm_nt_kernel<0><<<dim3(8, BQ / 64),   256, 0, stream>>>(visit, Wq, bq, qh);
    gemm_nt_kernel<0><<<dim3(8, NMEM / 64), 256, 0, stream>>>(Epat, Wk, bk, Kall);
    gemm_nt_kernel<0><<<dim3(8, NMEM / 64), 256, 0, stream>>>(Emed, Wv, bv, Vall);

    attn_kernel<<<BQ, 512, 0, stream>>>(qh, Kall, Vall, knn_idx, ctx);

    gemm_nt_kernel<0><<<dim3(8, BQ / 64), 256, 0, stream>>>(ctx, Wo, bo, attn_o);
    add_ln_kernel<<<BQ, 256, 0, stream>>>(visit, attn_o, ln1g, ln1b, x1);
    gemm_nt_kernel<1><<<dim3(8, BQ / 64), 256, 0, stream>>>(x1, W1, b1, h1);
    gemm_nt_kernel<0><<<dim3(8, BQ / 64), 256, 0, stream>>>(h1, W2, b2, ff);
    add_ln_kernel<<<BQ, 256, 0, stream>>>(x1, ff, ln2g, ln2b, out);
}

// Round 2
// 5620.370 us; speedup vs baseline: 1.5733x; 1.5733x over previous
//
#include <hip/hip_runtime.h>
#include <math.h>

#define BQ 4096
#define NMEM 32768
#define DD 512
#define TOPN 10
#define NQUART 4
#define QCOLS (NMEM / NQUART)    /* 8192 */
#define CANDQ 16                 /* candidates kept per quarter */
#define NCAND (NQUART * CANDQ)   /* 64 per row */
#define FINF 3.402823466e+38f

typedef __attribute__((ext_vector_type(8))) short    bf16x8;
typedef __attribute__((ext_vector_type(4))) float    f32x4;
typedef __attribute__((ext_vector_type(8))) unsigned short u16x8;

// ---------------- helpers ----------------
__device__ __forceinline__ unsigned short f2bf(float x) {
    unsigned int u = __float_as_uint(x);
    u += 0x7fffu + ((u >> 16) & 1u);          // round-to-nearest-even
    return (unsigned short)(u >> 16);
}
__device__ __forceinline__ float bf2f(unsigned short h) {
    return __uint_as_float(((unsigned int)h) << 16);
}
__device__ __forceinline__ void async_copy16(const void* gp, void* lp) {
    __builtin_amdgcn_global_load_lds(
        (const __attribute__((address_space(1))) void*)gp,
        (__attribute__((address_space(3))) void*)lp, 16, 0, 0);
}

__device__ __forceinline__ bool lt_si(float s, int j, float s2, int j2) {
    return (s < s2) || (s == s2 && j < j2);   // matches top_k tie-break
}
template<int KN>
__device__ __forceinline__ void topk_insert(float (&ts)[KN], int (&ti)[KN], float s, int j) {
    if (!lt_si(s, j, ts[KN-1], ti[KN-1])) return;
    #pragma unroll
    for (int p = KN-1; p > 0; --p) {
        if (lt_si(s, j, ts[p-1], ti[p-1])) { ts[p] = ts[p-1]; ti[p] = ti[p-1]; }
        else { ts[p] = s; ti[p] = j; return; }
    }
    ts[0] = s; ti[0] = j;
}

// ---------------- fp32 -> bf16 cast ----------------
__global__ __launch_bounds__(256) void cast_bf16_kernel(const float* __restrict__ in,
                                                        unsigned short* __restrict__ out) {
    int i = (blockIdx.x * 256 + threadIdx.x) * 4;
    float4 v = *(const float4*)(in + i);
    ushort4 o;
    o.x = f2bf(v.x); o.y = f2bf(v.y); o.z = f2bf(v.z); o.w = f2bf(v.w);
    *(ushort4*)(out + i) = o;
}

// ---------------- ||M_j||^2 ----------------
__global__ __launch_bounds__(256) void mnorm_kernel(const float* __restrict__ M,
                                                    float* __restrict__ mnorm) {
    int row = blockIdx.x * 4 + (threadIdx.x >> 6);
    int lane = threadIdx.x & 63;
    const float* mr = M + (size_t)row * DD;
    float s = 0.f;
    #pragma unroll
    for (int k = 0; k < DD; k += 64) { float v = mr[k + lane]; s = fmaf(v, v, s); }
    #pragma unroll
    for (int off = 32; off; off >>= 1) s += __shfl_xor(s, off, 64);
    if (lane == 0) mnorm[row] = s;
}

// ---------------- bf16 MFMA GEMM: S[4096, QCOLS] = Qb @ Mbq^T ----------------
// m97 structure: 128x128 tile, BK=64, 256 thr = 4 waves (2x2 of 64x64),
// global_load_lds width 16, 16x16x32 bf16 MFMA, row-major [row][64] LDS tiles.
__global__ __launch_bounds__(256) void gemm_s_kernel(
        const unsigned short* __restrict__ Qb,   // [4096][512]
        const unsigned short* __restrict__ Mbq,  // [QCOLS][512] (quarter base)
        unsigned short* __restrict__ S) {        // [4096][QCOLS]
    __shared__ __align__(16) unsigned short As[128 * 64];   // 16 KB
    __shared__ __align__(16) unsigned short Bs[128 * 64];   // 16 KB
    const int tid  = threadIdx.x;
    const int wave = tid >> 6, lane = tid & 63;
    const int quad = lane >> 4, c16 = lane & 15;
    const int m0 = blockIdx.y * 128, n0 = blockIdx.x * 128;
    const int wm0 = (wave >> 1) * 64, wn0 = (wave & 1) * 64;
    const int srow = wave * 32 + (lane >> 3);   // staging source row within tile
    const int schunk = lane & 7;                // 16B chunk within 128B row

    f32x4 acc[4][4] = {};

    for (int kt = 0; kt < DD; kt += 64) {
        __syncthreads();
        #pragma unroll
        for (int i = 0; i < 4; ++i) {
            const unsigned short* ga = Qb + (size_t)(m0 + srow + i * 8) * DD + kt + schunk * 8;
            async_copy16(ga, &As[(wave * 32 + i * 8) * 64]);
            const unsigned short* gb = Mbq + (size_t)(n0 + srow + i * 8) * DD + kt + schunk * 8;
            async_copy16(gb, &Bs[(wave * 32 + i * 8) * 64]);
        }
        __syncthreads();
        #pragma unroll
        for (int ks = 0; ks < 64; ks += 32) {
            bf16x8 af[4], bff[4];
            #pragma unroll
            for (int mt = 0; mt < 4; ++mt)
                af[mt] = *(const bf16x8*)&As[(wm0 + mt * 16 + c16) * 64 + ks + quad * 8];
            #pragma unroll
            for (int nt = 0; nt < 4; ++nt)
                bff[nt] = *(const bf16x8*)&Bs[(wn0 + nt * 16 + c16) * 64 + ks + quad * 8];
            #pragma unroll
            for (int mt = 0; mt < 4; ++mt)
                #pragma unroll
                for (int nt = 0; nt < 4; ++nt)
                    acc[mt][nt] = __builtin_amdgcn_mfma_f32_16x16x32_bf16(
                        af[mt], bff[nt], acc[mt][nt], 0, 0, 0);
        }
    }
    // C/D layout: col = lane&15, row = quad*4 + reg   [m89-verified]
    #pragma unroll
    for (int mt = 0; mt < 4; ++mt)
        #pragma unroll
        for (int nt = 0; nt < 4; ++nt) {
            size_t rbase = (size_t)(m0 + wm0 + mt * 16 + quad * 4) * QCOLS
                         + n0 + wn0 + nt * 16 + c16;
            #pragma unroll
            for (int r = 0; r < 4; ++r)
                S[rbase + (size_t)r * QCOLS] = f2bf(acc[mt][nt][r]);
        }
}

// ---------------- per-quarter top-16 selection ----------------
// score = mnorm[col] - 2 * S (bf16 dot). One block per row.
__global__ __launch_bounds__(256) void select_kernel(
        const unsigned short* __restrict__ S,     // [4096][QCOLS]
        const float* __restrict__ mnorm,
        int col0,                                  // quarter * QCOLS
        int* __restrict__ cand) {                  // [4096][NCAND]
    const int row = blockIdx.x, t = threadIdx.x;
    float ts[CANDQ]; int ti[CANDQ];
    #pragma unroll
    for (int p = 0; p < CANDQ; ++p) { ts[p] = FINF; ti[p] = 0x7fffffff; }
    #pragma unroll
    for (int j = 0; j < QCOLS / 2048; ++j) {
        int cb = t * 8 + j * 2048;
        u16x8 v = *(const u16x8*)&S[(size_t)row * QCOLS + cb];
        #pragma unroll
        for (int e = 0; e < 8; ++e) {
            int col = cb + e;
            float sc = fmaf(-2.f, bf2f(v[e]), mnorm[col0 + col]);
            topk_insert<CANDQ>(ts, ti, sc, col0 + col);
        }
    }
    __shared__ float ms[256][CANDQ];   // 16 KB
    __shared__ int   mi[256][CANDQ];   // 16 KB
    #pragma unroll
    for (int p = 0; p < CANDQ; ++p) { ms[t][p] = ts[p]; mi[t][p] = ti[p]; }
    __syncthreads();
    if (t < 16) {
        float fs[CANDQ]; int fi[CANDQ];
        #pragma unroll
        for (int p = 0; p < CANDQ; ++p) { fs[p] = FINF; fi[p] = 0x7fffffff; }
        for (int k = 0; k < 16; ++k) {
            int src = t + k * 16;
            #pragma unroll
            for (int p = 0; p < CANDQ; ++p)
                topk_insert<CANDQ>(fs, fi, ms[src][p], mi[src][p]);
        }
        #pragma unroll
        for (int p = 0; p < CANDQ; ++p) { ms[t][p] = fs[p]; mi[t][p] = fi[p]; }
    }
    __syncthreads();
    if (t == 0) {
        float fs[CANDQ]; int fi[CANDQ];
        #pragma unroll
        for (int p = 0; p < CANDQ; ++p) { fs[p] = FINF; fi[p] = 0x7fffffff; }
        for (int k = 0; k < 16; ++k)
            #pragma unroll
            for (int p = 0; p < CANDQ; ++p)
                topk_insert<CANDQ>(fs, fi, ms[k][p], mi[k][p]);
        int qoff = (col0 / QCOLS) * CANDQ;
        #pragma unroll
        for (int p = 0; p < CANDQ; ++p) cand[row * NCAND + qoff + p] = fi[p];
    }
}

// ---------------- exact fp32 rescore of 64 candidates -> top-10 ----------------
__global__ __launch_bounds__(256) void rescore_kernel(
        const float* __restrict__ Q, const float* __restrict__ Mm,
        const float* __restrict__ mnorm, const int* __restrict__ cand,
        int* __restrict__ knn_idx) {
    const int row = blockIdx.x;
    const int wave = threadIdx.x >> 6, lane = threadIdx.x & 63;
    float4 q0 = *(const float4*)(Q + (size_t)row * DD + lane * 8);
    float4 q1 = *(const float4*)(Q + (size_t)row * DD + lane * 8 + 4);
    __shared__ float d2s[NCAND];
    __shared__ int   ids[NCAND];
    for (int c = wave; c < NCAND; c += 4) {
        int j = cand[row * NCAND + c];
        const float* mr = Mm + (size_t)j * DD;
        float4 m0 = *(const float4*)(mr + lane * 8);
        float4 m1 = *(const float4*)(mr + lane * 8 + 4);
        float dot = q0.x*m0.x + q0.y*m0.y + q0.z*m0.z + q0.w*m0.w
                  + q1.x*m1.x + q1.y*m1.y + q1.z*m1.z + q1.w*m1.w;
        #pragma unroll
        for (int off = 32; off; off >>= 1) dot += __shfl_xor(dot, off, 64);
        if (lane == 0) { d2s[c] = fmaf(-2.f, dot, mnorm[j]); ids[c] = j; }
    }
    __syncthreads();
    if (threadIdx.x == 0) {
        float ts[TOPN]; int ti[TOPN];
        #pragma unroll
        for (int p = 0; p < TOPN; ++p) { ts[p] = FINF; ti[p] = 0x7fffffff; }
        for (int c = 0; c < NCAND; ++c) topk_insert<TOPN>(ts, ti, d2s[c], ids[c]);
        #pragma unroll
        for (int p = 0; p < TOPN; ++p) knn_idx[row * TOPN + p] = ti[p];
    }
}

// ---------------- fp32 GEMM: C[M,512] = A[M,512] @ Bw[512,512]^T + bias ----------------
template<int ACT>   // 0 = none, 1 = leaky_relu(0.01)
__global__ __launch_bounds__(256) void gemm_nt_kernel(
        const float* __restrict__ A, const float* __restrict__ Bw,
        const float* __restrict__ bias, float* __restrict__ C) {
    __shared__ float As[16][68];
    __shared__ float Bs[16][68];
    const int tid = threadIdx.x;
    const int tr = tid >> 4, tc = tid & 15;
    const int m0 = blockIdx.y << 6;
    const int n0 = blockIdx.x << 6;
    const int lrow = tid >> 2;
    const int lkc  = (tid & 3) << 2;
    float acc[4][4] = {};
    for (int kt = 0; kt < DD; kt += 16) {
        __syncthreads();
        {
            float4 va = *(const float4*)(A  + (size_t)(m0 + lrow) * DD + kt + lkc);
            As[lkc+0][lrow] = va.x; As[lkc+1][lrow] = va.y;
            As[lkc+2][lrow] = va.z; As[lkc+3][lrow] = va.w;
            float4 vb = *(const float4*)(Bw + (size_t)(n0 + lrow) * DD + kt + lkc);
            Bs[lkc+0][lrow] = vb.x; Bs[lkc+1][lrow] = vb.y;
            Bs[lkc+2][lrow] = vb.z; Bs[lkc+3][lrow] = vb.w;
        }
        __syncthreads();
        #pragma unroll
        for (int k = 0; k < 16; ++k) {
            float4 a = *(const float4*)&As[k][tr << 2];
            float4 b = *(const float4*)&Bs[k][tc << 2];
            acc[0][0]=fmaf(a.x,b.x,acc[0][0]); acc[0][1]=fmaf(a.x,b.y,acc[0][1]);
            acc[0][2]=fmaf(a.x,b.z,acc[0][2]); acc[0][3]=fmaf(a.x,b.w,acc[0][3]);
            acc[1][0]=fmaf(a.y,b.x,acc[1][0]); acc[1][1]=fmaf(a.y,b.y,acc[1][1]);
            acc[1][2]=fmaf(a.y,b.z,acc[1][2]); acc[1][3]=fmaf(a.y,b.w,acc[1][3]);
            acc[2][0]=fmaf(a.z,b.x,acc[2][0]); acc[2][1]=fmaf(a.z,b.y,acc[2][1]);
            acc[2][2]=fmaf(a.z,b.z,acc[2][2]); acc[2][3]=fmaf(a.z,b.w,acc[2][3]);
            acc[3][0]=fmaf(a.w,b.x,acc[3][0]); acc[3][1]=fmaf(a.w,b.y,acc[3][1]);
            acc[3][2]=fmaf(a.w,b.z,acc[3][2]); acc[3][3]=fmaf(a.w,b.w,acc[3][3]);
        }
    }
    float4 bv = *(const float4*)(bias + n0 + (tc << 2));
    #pragma unroll
    for (int i = 0; i < 4; ++i) {
        float4 o;
        o.x = acc[i][0] + bv.x; o.y = acc[i][1] + bv.y;
        o.z = acc[i][2] + bv.z; o.w = acc[i][3] + bv.w;
        if (ACT == 1) {
            o.x = o.x >= 0.f ? o.x : 0.01f * o.x;
            o.y = o.y >= 0.f ? o.y : 0.01f * o.y;
            o.z = o.z >= 0.f ? o.z : 0.01f * o.z;
            o.w = o.w >= 0.f ? o.w : 0.01f * o.w;
        }
        *(float4*)(C + (size_t)(m0 + (tr << 2) + i) * DD + n0 + (tc << 2)) = o;
    }
}

// ---------------- attention: one block per query row, one wave per head ----------------
__global__ __launch_bounds__(512) void attn_kernel(
        const float* __restrict__ qh, const float* __restrict__ Kall,
        const float* __restrict__ Vall, const int* __restrict__ knn_idx,
        float* __restrict__ ctx) {
    const int b = blockIdx.x;
    const int h = threadIdx.x >> 6;
    const int l = threadIdx.x & 63;
    const int col = (h << 6) + l;
    int idxs[TOPN];
    #pragma unroll
    for (int n = 0; n < TOPN; ++n) idxs[n] = knn_idx[b * TOPN + n];
    const float q = qh[(size_t)b * DD + col];
    float sc[TOPN];
    #pragma unroll
    for (int n = 0; n < TOPN; ++n) {
        float p = q * Kall[(size_t)idxs[n] * DD + col];
        #pragma unroll
        for (int off = 32; off; off >>= 1) p += __shfl_xor(p, off, 64);
        sc[n] = p * 0.125f;
    }
    float mx = sc[0];
    #pragma unroll
    for (int n = 1; n < TOPN; ++n) mx = fmaxf(mx, sc[n]);
    float se = 0.f;
    #pragma unroll
    for (int n = 0; n < TOPN; ++n) { sc[n] = expf(sc[n] - mx); se += sc[n]; }
    const float inv = 1.f / se;
    float o = 0.f;
    #pragma unroll
    for (int n = 0; n < TOPN; ++n)
        o = fmaf(sc[n] * inv, Vall[(size_t)idxs[n] * DD + col], o);
    ctx[(size_t)b * DD + col] = o;
}

// ---------------- residual add + layernorm ----------------
__global__ __launch_bounds__(256) void add_ln_kernel(
        const float* __restrict__ X, const float* __restrict__ Y,
        const float* __restrict__ g, const float* __restrict__ be,
        float* __restrict__ out) {
    const int row = blockIdx.x;
    const int t = threadIdx.x;
    const size_t base = (size_t)row * DD;
    float v0 = X[base + t]       + Y[base + t];
    float v1 = X[base + 256 + t] + Y[base + 256 + t];
    float s = v0 + v1, sq = v0 * v0 + v1 * v1;
    #pragma unroll
    for (int off = 32; off; off >>= 1) { s += __shfl_xor(s, off, 64); sq += __shfl_xor(sq, off, 64); }
    __shared__ float rs[4], rq[4];
    const int w = t >> 6, l = t & 63;
    if (l == 0) { rs[w] = s; rq[w] = sq; }
    __syncthreads();
    float tot  = rs[0] + rs[1] + rs[2] + rs[3];
    float totq = rq[0] + rq[1] + rq[2] + rq[3];
    float mu = tot * (1.f / DD);
    float var = totq * (1.f / DD) - mu * mu;
    float rstd = rsqrtf(var + 1e-5f);
    out[base + t]       = (v0 - mu) * rstd * g[t]       + be[t];
    out[base + 256 + t] = (v1 - mu) * rstd * g[256 + t] + be[256 + t];
}

// ---------------- launch ----------------
extern "C" void kernel_launch(void* const* d_in, const int* in_sizes, int n_in,
                              void* d_out, int out_size, void* d_ws, size_t ws_size,
                              hipStream_t stream) {
    const float* visit = (const float*)d_in[0];
    const float* Epat  = (const float*)d_in[1];
    const float* Emed  = (const float*)d_in[2];
    const float* Wq = (const float*)d_in[3];
    const float* Wk = (const float*)d_in[4];
    const float* Wv = (const float*)d_in[5];
    const float* bq = (const float*)d_in[6];
    const float* bk = (const float*)d_in[7];
    const float* bv = (const float*)d_in[8];
    const float* Wo = (const float*)d_in[9];
    const float* bo = (const float*)d_in[10];
    const float* W1 = (const float*)d_in[11];
    const float* b1 = (const float*)d_in[12];
    const float* W2 = (const float*)d_in[13];
    const float* b2 = (const float*)d_in[14];
    const float* ln1g = (const float*)d_in[15];
    const float* ln1b = (const float*)d_in[16];
    const float* ln2g = (const float*)d_in[17];
    const float* ln2b = (const float*)d_in[18];
    float* out = (float*)d_out;

    // ---- workspace layout (bytes). Peak ~170 MB (round-1 used ~177 MB OK).
    // Sq (64MB) aliases KallRegion; Qb/Mb (36MB) alias VallRegion — both are
    // written only after the kNN phase completes (stream-ordered).
    char* base = (char*)d_ws;
    float* mnorm   = (float*)(base);                       // 128 KB
    int*   cand    = (int*)  (base + (1u<<20));            // 1 MB
    int*   knn_idx = (int*)  (base + (2u<<20));            // 160 KB
    float* qh      = (float*)(base + (3u<<20));            // 8 MB
    float* ctx     = (float*)(base + (11u<<20));           // 8 MB
    float* attn_o  = (float*)(base + (19u<<20));           // 8 MB
    float* x1      = (float*)(base + (27u<<20));           // 8 MB
    float* h1      = (float*)(base + (35u<<20));           // 8 MB
    float* ff      = (float*)(base + (43u<<20));           // 8 MB
    char*  KallReg = base + (51u<<20);                     // 64 MB
    char*  VallReg = base + (115u<<20);                    // 64 MB  (end: 179 MB)
    float* Kall = (float*)KallReg;
    float* Vall = (float*)VallReg;
    unsigned short* Sq = (unsigned short*)KallReg;         // alias (kNN phase)
    unsigned short* Qb = (unsigned short*)VallReg;         // alias (kNN phase)
    unsigned short* Mb = (unsigned short*)(VallReg + (4u<<20));

    // ---- kNN path: bf16 MFMA coarse scores -> top-16/quarter -> fp32 rescore
    mnorm_kernel<<<NMEM / 4, 256, 0, stream>>>(Epat, mnorm);
    cast_bf16_kernel<<<(BQ * DD) / 1024,   256, 0, stream>>>(visit, Qb);
    cast_bf16_kernel<<<(NMEM * DD) / 1024, 256, 0, stream>>>(Epat, Mb);
    for (int q = 0; q < NQUART; ++q) {
        gemm_s_kernel<<<dim3(QCOLS / 128, BQ / 128), 256, 0, stream>>>(
            Qb, Mb + (size_t)q * QCOLS * DD, Sq);
        select_kernel<<<BQ, 256, 0, stream>>>(Sq, mnorm, q * QCOLS, cand);
    }
    rescore_kernel<<<BQ, 256, 0, stream>>>(visit, Epat, mnorm, cand, knn_idx);

    // ---- projections (fp32 VALU for now; MFMA conversion is next)
    gemm_nt_kernel<0><<<dim3(8, BQ / 64),   256, 0, stream>>>(visit, Wq, bq, qh);
    gemm_nt_kernel<0><<<dim3(8, NMEM / 64), 256, 0, stream>>>(Epat, Wk, bk, Kall);
    gemm_nt_kernel<0><<<dim3(8, NMEM / 64), 256, 0, stream>>>(Emed, Wv, bv, Vall);

    attn_kernel<<<BQ, 512, 0, stream>>>(qh, Kall, Vall, knn_idx, ctx);

    gemm_nt_kernel<0><<<dim3(8, BQ / 64), 256, 0, stream>>>(ctx, Wo, bo, attn_o);
    add_ln_kernel<<<BQ, 256, 0, stream>>>(visit, attn_o, ln1g, ln1b, x1);
    gemm_nt_kernel<1><<<dim3(8, BQ / 64), 256, 0, stream>>>(x1, W1, b1, h1);
    gemm_nt_kernel<0><<<dim3(8, BQ / 64), 256, 0, stream>>>(h1, W2, b2, ff);
    add_ln_kernel<<<BQ, 256, 0, stream>>>(x1, ff, ln2g, ln2b, out);
}

// Round 3
// 1056.994 us; speedup vs baseline: 8.3657x; 5.3173x over previous
//
#include <hip/hip_runtime.h>
#include <math.h>

#define BQ 4096
#define NMEM 32768
#define DD 512
#define TOPN 10
#define NQUART 4
#define QCOLS (NMEM / NQUART)    /* 8192 */
#define CANDQ 16                 /* candidates kept per quarter */
#define NCAND (NQUART * CANDQ)   /* 64 per row */
#define LK 6                     /* per-lane top-K in select */
#define FINF 3.402823466e+38f
#define IMAX 0x7fffffff

typedef __attribute__((ext_vector_type(8))) short    bf16x8;
typedef __attribute__((ext_vector_type(4))) float    f32x4;
typedef __attribute__((ext_vector_type(8))) unsigned short u16x8;

// ---------------- helpers ----------------
__device__ __forceinline__ unsigned short f2bf(float x) {
    unsigned int u = __float_as_uint(x);
    u += 0x7fffu + ((u >> 16) & 1u);          // round-to-nearest-even
    return (unsigned short)(u >> 16);
}
__device__ __forceinline__ float bf2f(unsigned short h) {
    return __uint_as_float(((unsigned int)h) << 16);
}
__device__ __forceinline__ void async_copy16(const void* gp, void* lp) {
    __builtin_amdgcn_global_load_lds(
        (const __attribute__((address_space(1))) void*)gp,
        (__attribute__((address_space(3))) void*)lp, 16, 0, 0);
}

__device__ __forceinline__ bool lt_si(float s, int j, float s2, int j2) {
    return (s < s2) || (s == s2 && j < j2);   // matches top_k tie-break
}
template<int KN>
__device__ __forceinline__ void topk_insert(float (&ts)[KN], int (&ti)[KN], float s, int j) {
    if (!lt_si(s, j, ts[KN-1], ti[KN-1])) return;
    #pragma unroll
    for (int p = KN-1; p > 0; --p) {
        if (lt_si(s, j, ts[p-1], ti[p-1])) { ts[p] = ts[p-1]; ti[p] = ti[p-1]; }
        else { ts[p] = s; ti[p] = j; return; }
    }
    ts[0] = s; ti[0] = j;
}

// ---------------- fp32 -> bf16 cast ----------------
__global__ __launch_bounds__(256) void cast_bf16_kernel(const float* __restrict__ in,
                                                        unsigned short* __restrict__ out) {
    int i = (blockIdx.x * 256 + threadIdx.x) * 4;
    float4 v = *(const float4*)(in + i);
    ushort4 o;
    o.x = f2bf(v.x); o.y = f2bf(v.y); o.z = f2bf(v.z); o.w = f2bf(v.w);
    *(ushort4*)(out + i) = o;
}

// ---------------- ||M_j||^2 ----------------
__global__ __launch_bounds__(256) void mnorm_kernel(const float* __restrict__ M,
                                                    float* __restrict__ mnorm) {
    int row = blockIdx.x * 4 + (threadIdx.x >> 6);
    int lane = threadIdx.x & 63;
    const float* mr = M + (size_t)row * DD;
    float s = 0.f;
    #pragma unroll
    for (int k = 0; k < DD; k += 64) { float v = mr[k + lane]; s = fmaf(v, v, s); }
    #pragma unroll
    for (int off = 32; off; off >>= 1) s += __shfl_xor(s, off, 64);
    if (lane == 0) mnorm[row] = s;
}

// ---------------- unified bf16 MFMA GEMM (m97 structure) ----------------
// C[M,N] (ldc) = A[M,512]bf16 @ B[N,512]bf16^T (+bias) (+leaky) -> fp32 or bf16
// 128x128 tile, BK=64, 256 thr = 4 waves (2x2 of 64x64), 16x16x32 bf16 MFMA.
template<int ACT, int HAS_BIAS, int OUT_BF16>
__global__ __launch_bounds__(256) void gemm_bf16_nt(
        const unsigned short* __restrict__ A,
        const unsigned short* __restrict__ B,
        const float* __restrict__ bias,
        void* __restrict__ Cout, int ldc) {
    __shared__ __align__(16) unsigned short As[128 * 64];   // 16 KB
    __shared__ __align__(16) unsigned short Bs[128 * 64];   // 16 KB
    const int tid  = threadIdx.x;
    const int wave = tid >> 6, lane = tid & 63;
    const int quad = lane >> 4, c16 = lane & 15;
    const int m0 = blockIdx.y * 128, n0 = blockIdx.x * 128;
    const int wm0 = (wave >> 1) * 64, wn0 = (wave & 1) * 64;
    const int srow = wave * 32 + (lane >> 3);
    const int schunk = lane & 7;

    f32x4 acc[4][4] = {};

    for (int kt = 0; kt < DD; kt += 64) {
        __syncthreads();
        #pragma unroll
        for (int i = 0; i < 4; ++i) {
            const unsigned short* ga = A + (size_t)(m0 + srow + i * 8) * DD + kt + schunk * 8;
            async_copy16(ga, &As[(wave * 32 + i * 8) * 64]);
            const unsigned short* gb = B + (size_t)(n0 + srow + i * 8) * DD + kt + schunk * 8;
            async_copy16(gb, &Bs[(wave * 32 + i * 8) * 64]);
        }
        __syncthreads();
        #pragma unroll
        for (int ks = 0; ks < 64; ks += 32) {
            bf16x8 af[4], bff[4];
            #pragma unroll
            for (int mt = 0; mt < 4; ++mt)
                af[mt] = *(const bf16x8*)&As[(wm0 + mt * 16 + c16) * 64 + ks + quad * 8];
            #pragma unroll
            for (int nt = 0; nt < 4; ++nt)
                bff[nt] = *(const bf16x8*)&Bs[(wn0 + nt * 16 + c16) * 64 + ks + quad * 8];
            #pragma unroll
            for (int mt = 0; mt < 4; ++mt)
                #pragma unroll
                for (int nt = 0; nt < 4; ++nt)
                    acc[mt][nt] = __builtin_amdgcn_mfma_f32_16x16x32_bf16(
                        af[mt], bff[nt], acc[mt][nt], 0, 0, 0);
        }
    }
    // C/D layout: col = lane&15, row = quad*4 + reg   [m89-verified]
    #pragma unroll
    for (int nt = 0; nt < 4; ++nt) {
        int ncol = n0 + wn0 + nt * 16 + c16;
        float bv = HAS_BIAS ? bias[ncol] : 0.f;
        #pragma unroll
        for (int mt = 0; mt < 4; ++mt) {
            size_t rbase = (size_t)(m0 + wm0 + mt * 16 + quad * 4) * ldc + ncol;
            #pragma unroll
            for (int r = 0; r < 4; ++r) {
                float v = acc[mt][nt][r] + bv;
                if (ACT == 1) v = v >= 0.f ? v : 0.01f * v;
                if (OUT_BF16) ((unsigned short*)Cout)[rbase + (size_t)r * ldc] = f2bf(v);
                else          ((float*)Cout)[rbase + (size_t)r * ldc] = v;
            }
        }
    }
}

// ---------------- per-quarter top-16 selection (wave-parallel) ----------------
// One block (4 waves) per row. Lane: branchless top-6 over 32 elems;
// wave: 16 rounds of lexicographic argmin extraction; block: 64->16 merge.
__global__ __launch_bounds__(256) void select_kernel(
        const unsigned short* __restrict__ S,     // [4096][QCOLS] bf16
        const float* __restrict__ mnorm,
        int col0,
        int* __restrict__ cand) {                  // [4096][NCAND]
    const int row = blockIdx.x;
    const int wave = threadIdx.x >> 6, lane = threadIdx.x & 63;

    float ts[LK]; int ti[LK];
    #pragma unroll
    for (int p = 0; p < LK; ++p) { ts[p] = FINF; ti[p] = IMAX; }

    const unsigned short* Srow = S + (size_t)row * QCOLS + wave * 2048;
    #pragma unroll
    for (int c = 0; c < 4; ++c) {
        int cb = c * 512 + lane * 8;               // within wave's 2048 span
        u16x8 v = *(const u16x8*)&Srow[cb];
        float4 mn0 = *(const float4*)&mnorm[col0 + wave * 2048 + cb];
        float4 mn1 = *(const float4*)&mnorm[col0 + wave * 2048 + cb + 4];
        float sc[8];
        sc[0] = fmaf(-2.f, bf2f(v[0]), mn0.x); sc[1] = fmaf(-2.f, bf2f(v[1]), mn0.y);
        sc[2] = fmaf(-2.f, bf2f(v[2]), mn0.z); sc[3] = fmaf(-2.f, bf2f(v[3]), mn0.w);
        sc[4] = fmaf(-2.f, bf2f(v[4]), mn1.x); sc[5] = fmaf(-2.f, bf2f(v[5]), mn1.y);
        sc[6] = fmaf(-2.f, bf2f(v[6]), mn1.z); sc[7] = fmaf(-2.f, bf2f(v[7]), mn1.w);
        #pragma unroll
        for (int e = 0; e < 8; ++e) {
            float s = sc[e];
            int j = col0 + wave * 2048 + cb + e;
            // branchless insert into ascending top-6
            bool cm[LK];
            #pragma unroll
            for (int p = 0; p < LK; ++p) cm[p] = s < ts[p];
            #pragma unroll
            for (int p = LK - 1; p > 0; --p) {
                float tns = cm[p] ? s : ts[p];  int tni = cm[p] ? j : ti[p];
                ts[p] = cm[p-1] ? ts[p-1] : tns;
                ti[p] = cm[p-1] ? ti[p-1] : tni;
            }
            ts[0] = cm[0] ? s : ts[0];
            ti[0] = cm[0] ? j : ti[0];
        }
    }

    // wave-level: extract top-16 via argmin rounds
    float ks = FINF; int ki = IMAX;
    #pragma unroll
    for (int r = 0; r < 16; ++r) {
        float ms = ts[0]; int mi = ti[0];
        #pragma unroll
        for (int off = 1; off < 64; off <<= 1) {
            float os = __shfl_xor(ms, off, 64);
            int   oi = __shfl_xor(mi, off, 64);
            bool t = (os < ms) || (os == ms && oi < mi);
            ms = t ? os : ms; mi = t ? oi : mi;
        }
        bool win = (ti[0] == mi);                  // column idx unique -> exact
        #pragma unroll
        for (int p = 0; p < LK - 1; ++p) {
            ts[p] = win ? ts[p+1] : ts[p];
            ti[p] = win ? ti[p+1] : ti[p];
        }
        ts[LK-1] = win ? FINF : ts[LK-1];
        ti[LK-1] = win ? IMAX : ti[LK-1];
        if (lane == r) { ks = ms; ki = mi; }
    }
    __shared__ float ss[64];
    __shared__ int   si[64];
    if (lane < 16) { ss[wave * 16 + lane] = ks; si[wave * 16 + lane] = ki; }
    __syncthreads();

    if (wave == 0) {
        float s2 = ss[lane]; int i2 = si[lane];
        float fs = FINF; int fi = IMAX;
        #pragma unroll
        for (int r = 0; r < 16; ++r) {
            float ms = s2; int mi = i2;
            #pragma unroll
            for (int off = 1; off < 64; off <<= 1) {
                float os = __shfl_xor(ms, off, 64);
                int   oi = __shfl_xor(mi, off, 64);
                bool t = (os < ms) || (os == ms && oi < mi);
                ms = t ? os : ms; mi = t ? oi : mi;
            }
            bool win = (i2 == mi);
            s2 = win ? FINF : s2; i2 = win ? IMAX : i2;
            if (lane == r) { fs = ms; fi = mi; }
        }
        if (lane < 16)
            cand[row * NCAND + (col0 / QCOLS) * CANDQ + lane] = fi;
    }
}

// ---------------- exact fp32 rescore of 64 candidates -> top-10 ----------------
__global__ __launch_bounds__(256) void rescore_kernel(
        const float* __restrict__ Q, const float* __restrict__ Mm,
        const float* __restrict__ mnorm, const int* __restrict__ cand,
        int* __restrict__ knn_idx) {
    const int row = blockIdx.x;
    const int wave = threadIdx.x >> 6, lane = threadIdx.x & 63;
    float4 q0 = *(const float4*)(Q + (size_t)row * DD + lane * 8);
    float4 q1 = *(const float4*)(Q + (size_t)row * DD + lane * 8 + 4);
    __shared__ float d2s[NCAND];
    __shared__ int   ids[NCAND];
    for (int c = wave; c < NCAND; c += 4) {
        int j = cand[row * NCAND + c];
        const float* mr = Mm + (size_t)j * DD;
        float4 m0 = *(const float4*)(mr + lane * 8);
        float4 m1 = *(const float4*)(mr + lane * 8 + 4);
        float dot = q0.x*m0.x + q0.y*m0.y + q0.z*m0.z + q0.w*m0.w
                  + q1.x*m1.x + q1.y*m1.y + q1.z*m1.z + q1.w*m1.w;
        #pragma unroll
        for (int off = 32; off; off >>= 1) dot += __shfl_xor(dot, off, 64);
        if (lane == 0) { d2s[c] = fmaf(-2.f, dot, mnorm[j]); ids[c] = j; }
    }
    __syncthreads();
    if (threadIdx.x == 0) {
        float ts[TOPN]; int ti[TOPN];
        #pragma unroll
        for (int p = 0; p < TOPN; ++p) { ts[p] = FINF; ti[p] = IMAX; }
        for (int c = 0; c < NCAND; ++c) topk_insert<TOPN>(ts, ti, d2s[c], ids[c]);
        #pragma unroll
        for (int p = 0; p < TOPN; ++p) knn_idx[row * TOPN + p] = ti[p];
    }
}

// ---------------- attention: one block per query row, one wave per head ----------------
__global__ __launch_bounds__(512) void attn_kernel(
        const float* __restrict__ qh, const unsigned short* __restrict__ Kall,
        const unsigned short* __restrict__ Vall, const int* __restrict__ knn_idx,
        float* __restrict__ ctx) {
    const int b = blockIdx.x;
    const int h = threadIdx.x >> 6;
    const int l = threadIdx.x & 63;
    const int col = (h << 6) + l;
    int idxs[TOPN];
    #pragma unroll
    for (int n = 0; n < TOPN; ++n) idxs[n] = knn_idx[b * TOPN + n];
    const float q = qh[(size_t)b * DD + col];
    float sc[TOPN];
    #pragma unroll
    for (int n = 0; n < TOPN; ++n) {
        float p = q * bf2f(Kall[(size_t)idxs[n] * DD + col]);
        #pragma unroll
        for (int off = 32; off; off >>= 1) p += __shfl_xor(p, off, 64);
        sc[n] = p * 0.125f;
    }
    float mx = sc[0];
    #pragma unroll
    for (int n = 1; n < TOPN; ++n) mx = fmaxf(mx, sc[n]);
    float se = 0.f;
    #pragma unroll
    for (int n = 0; n < TOPN; ++n) { sc[n] = expf(sc[n] - mx); se += sc[n]; }
    const float inv = 1.f / se;
    float o = 0.f;
    #pragma unroll
    for (int n = 0; n < TOPN; ++n)
        o = fmaf(sc[n] * inv, bf2f(Vall[(size_t)idxs[n] * DD + col]), o);
    ctx[(size_t)b * DD + col] = o;
}

// ---------------- residual add + layernorm ----------------
__global__ __launch_bounds__(256) void add_ln_kernel(
        const float* __restrict__ X, const float* __restrict__ Y,
        const float* __restrict__ g, const float* __restrict__ be,
        float* __restrict__ out) {
    const int row = blockIdx.x;
    const int t = threadIdx.x;
    const size_t base = (size_t)row * DD;
    float v0 = X[base + t]       + Y[base + t];
    float v1 = X[base + 256 + t] + Y[base + 256 + t];
    float s = v0 + v1, sq = v0 * v0 + v1 * v1;
    #pragma unroll
    for (int off = 32; off; off >>= 1) { s += __shfl_xor(s, off, 64); sq += __shfl_xor(sq, off, 64); }
    __shared__ float rs[4], rq[4];
    const int w = t >> 6, l = t & 63;
    if (l == 0) { rs[w] = s; rq[w] = sq; }
    __syncthreads();
    float tot  = rs[0] + rs[1] + rs[2] + rs[3];
    float totq = rq[0] + rq[1] + rq[2] + rq[3];
    float mu = tot * (1.f / DD);
    float var = totq * (1.f / DD) - mu * mu;
    float rstd = rsqrtf(var + 1e-5f);
    out[base + t]       = (v0 - mu) * rstd * g[t]       + be[t];
    out[base + 256 + t] = (v1 - mu) * rstd * g[256 + t] + be[256 + t];
}

// ---------------- launch ----------------
extern "C" void kernel_launch(void* const* d_in, const int* in_sizes, int n_in,
                              void* d_out, int out_size, void* d_ws, size_t ws_size,
                              hipStream_t stream) {
    const float* visit = (const float*)d_in[0];
    const float* Epat  = (const float*)d_in[1];
    const float* Emed  = (const float*)d_in[2];
    const float* Wq = (const float*)d_in[3];
    const float* Wk = (const float*)d_in[4];
    const float* Wv = (const float*)d_in[5];
    const float* bq = (const float*)d_in[6];
    const float* bk = (const float*)d_in[7];
    const float* bv = (const float*)d_in[8];
    const float* Wo = (const float*)d_in[9];
    const float* bo = (const float*)d_in[10];
    const float* W1 = (const float*)d_in[11];
    const float* b1 = (const float*)d_in[12];
    const float* W2 = (const float*)d_in[13];
    const float* b2 = (const float*)d_in[14];
    const float* ln1g = (const float*)d_in[15];
    const float* ln1b = (const float*)d_in[16];
    const float* ln2g = (const float*)d_in[17];
    const float* ln2b = (const float*)d_in[18];
    float* out = (float*)d_out;

    // ---- workspace layout, ~174 MB peak (round-1 used 179 MB OK) ----
    char* base = (char*)d_ws;
    const size_t MB = 1u << 20;
    float* mnorm   = (float*)(base);                    // 128 KB
    int*   cand    = (int*)  (base + 1*MB);             // 1 MB
    int*   knn_idx = (int*)  (base + 2*MB);             // 160 KB
    float* qh      = (float*)(base + 3*MB);             // 8 MB
    float* attn_o  = qh;                                // alias: qh dead after attn
    float* ctx     = (float*)(base + 11*MB);            // 8 MB
    float* x1      = ctx;                               // alias: ctx dead after cast
    float* ff      = (float*)(base + 19*MB);            // 8 MB
    unsigned short* Qb    = (unsigned short*)(base + 27*MB);  // 4 MB (visit bf16)
    unsigned short* ctx_b = (unsigned short*)(base + 31*MB);  // 4 MB
    unsigned short* x1_b  = (unsigned short*)(base + 35*MB);  // 4 MB
    unsigned short* h1_b  = (unsigned short*)(base + 39*MB);  // 4 MB
    unsigned short* Wq_b  = (unsigned short*)(base + 43*MB);  // 6 x 512 KB
    unsigned short* Wk_b  = Wq_b + 262144;
    unsigned short* Wv_b  = Wk_b + 262144;
    unsigned short* Wo_b  = Wv_b + 262144;
    unsigned short* W1_b  = Wo_b + 262144;
    unsigned short* W2_b  = W1_b + 262144;
    unsigned short* Mb     = (unsigned short*)(base + 46*MB); // 32 MB (Epat bf16)
    unsigned short* Emed_b = (unsigned short*)(base + 78*MB); // 32 MB
    // K|V region (64 MB bf16), aliased by Sq during the kNN phase
    unsigned short* Kall = (unsigned short*)(base + 110*MB);  // 32 MB
    unsigned short* Vall = Kall + (size_t)NMEM * DD;          // 32 MB
    unsigned short* Sq   = Kall;                              // alias (kNN phase only)

    // ---- casts + norms ----
    mnorm_kernel<<<NMEM / 4, 256, 0, stream>>>(Epat, mnorm);
    cast_bf16_kernel<<<(BQ * DD) / 1024,   256, 0, stream>>>(visit, Qb);
    cast_bf16_kernel<<<(NMEM * DD) / 1024, 256, 0, stream>>>(Epat, Mb);
    cast_bf16_kernel<<<(NMEM * DD) / 1024, 256, 0, stream>>>(Emed, Emed_b);
    cast_bf16_kernel<<<256, 256, 0, stream>>>(Wq, Wq_b);
    cast_bf16_kernel<<<256, 256, 0, stream>>>(Wk, Wk_b);
    cast_bf16_kernel<<<256, 256, 0, stream>>>(Wv, Wv_b);
    cast_bf16_kernel<<<256, 256, 0, stream>>>(Wo, Wo_b);
    cast_bf16_kernel<<<256, 256, 0, stream>>>(W1, W1_b);
    cast_bf16_kernel<<<256, 256, 0, stream>>>(W2, W2_b);

    // ---- kNN: bf16 MFMA coarse scores -> top-16/quarter -> fp32 rescore ----
    for (int q = 0; q < NQUART; ++q) {
        gemm_bf16_nt<0,0,1><<<dim3(QCOLS / 128, BQ / 128), 256, 0, stream>>>(
            Qb, Mb + (size_t)q * QCOLS * DD, nullptr, Sq, QCOLS);
        select_kernel<<<BQ, 256, 0, stream>>>(Sq, mnorm, q * QCOLS, cand);
    }
    rescore_kernel<<<BQ, 256, 0, stream>>>(visit, Epat, mnorm, cand, knn_idx);

    // ---- projections (all bf16 MFMA) ----
    gemm_bf16_nt<0,1,1><<<dim3(4, NMEM / 128), 256, 0, stream>>>(Mb,     Wk_b, bk, Kall, DD);
    gemm_bf16_nt<0,1,1><<<dim3(4, NMEM / 128), 256, 0, stream>>>(Emed_b, Wv_b, bv, Vall, DD);
    gemm_bf16_nt<0,1,0><<<dim3(4, BQ / 128),   256, 0, stream>>>(Qb,     Wq_b, bq, qh,   DD);

    attn_kernel<<<BQ, 512, 0, stream>>>(qh, Kall, Vall, knn_idx, ctx);
    cast_bf16_kernel<<<(BQ * DD) / 1024, 256, 0, stream>>>(ctx, ctx_b);

    gemm_bf16_nt<0,1,0><<<dim3(4, BQ / 128), 256, 0, stream>>>(ctx_b, Wo_b, bo, attn_o, DD);
    add_ln_kernel<<<BQ, 256, 0, stream>>>(visit, attn_o, ln1g, ln1b, x1);
    cast_bf16_kernel<<<(BQ * DD) / 1024, 256, 0, stream>>>(x1, x1_b);
    gemm_bf16_nt<1,1,1><<<dim3(4, BQ / 128), 256, 0, stream>>>(x1_b, W1_b, b1, h1_b, DD);
    gemm_bf16_nt<0,1,0><<<dim3(4, BQ / 128), 256, 0, stream>>>(h1_b, W2_b, b2, ff,   DD);
    add_ln_kernel<<<BQ, 256, 0, stream>>>(x1, ff, ln2g, ln2b, out);
}

// Round 5
// 762.414 us; speedup vs baseline: 11.5980x; 1.3864x over previous
//
#include <hip/hip_runtime.h>
#include <math.h>

#define BQ 4096
#define NMEM 32768
#define DD 512
#define TOPN 10
#define CB 256                   /* 128-col blocks over NMEM */
#define ENT 2048                 /* candidate entries per row = CB*8 */
#define NCF 16                   /* final candidates per row */
#define LK 6                     /* per-lane top-K in merge */
#define FINF 3.402823466e+38f
#define IMAX 0x7fffffff

typedef __attribute__((ext_vector_type(8))) short    bf16x8;
typedef __attribute__((ext_vector_type(4))) float    f32x4;

// ---------------- helpers ----------------
__device__ __forceinline__ unsigned short f2bf(float x) {
    unsigned int u = __float_as_uint(x);
    u += 0x7fffu + ((u >> 16) & 1u);          // round-to-nearest-even
    return (unsigned short)(u >> 16);
}
__device__ __forceinline__ float bf2f(unsigned short h) {
    return __uint_as_float(((unsigned int)h) << 16);
}
__device__ __forceinline__ void async_copy16(const void* gp, void* lp) {
    __builtin_amdgcn_global_load_lds(
        (const __attribute__((address_space(1))) void*)gp,
        (__attribute__((address_space(3))) void*)lp, 16, 0, 0);
}
__device__ __forceinline__ bool lt_si(float s, int j, float s2, int j2) {
    return (s < s2) || (s == s2 && j < j2);   // matches top_k tie-break
}
template<int KN>
__device__ __forceinline__ void topk_insert(float (&ts)[KN], int (&ti)[KN], float s, int j) {
    if (!lt_si(s, j, ts[KN-1], ti[KN-1])) return;
    #pragma unroll
    for (int p = KN-1; p > 0; --p) {
        if (lt_si(s, j, ts[p-1], ti[p-1])) { ts[p] = ts[p-1]; ti[p] = ti[p-1]; }
        else { ts[p] = s; ti[p] = j; return; }
    }
    ts[0] = s; ti[0] = j;
}

// ---------------- fp32 -> bf16 cast ----------------
__global__ __launch_bounds__(256) void cast_bf16_kernel(const float* __restrict__ in,
                                                        unsigned short* __restrict__ out) {
    int i = (blockIdx.x * 256 + threadIdx.x) * 4;
    float4 v = *(const float4*)(in + i);
    ushort4 o;
    o.x = f2bf(v.x); o.y = f2bf(v.y); o.z = f2bf(v.z); o.w = f2bf(v.w);
    *(ushort4*)(out + i) = o;
}

// ---------------- ||M_j||^2 ----------------
__global__ __launch_bounds__(256) void mnorm_kernel(const float* __restrict__ M,
                                                    float* __restrict__ mnorm) {
    int row = blockIdx.x * 4 + (threadIdx.x >> 6);
    int lane = threadIdx.x & 63;
    const float* mr = M + (size_t)row * DD;
    float s = 0.f;
    #pragma unroll
    for (int k = 0; k < DD; k += 64) { float v = mr[k + lane]; s = fmaf(v, v, s); }
    #pragma unroll
    for (int off = 32; off; off >>= 1) s += __shfl_xor(s, off, 64);
    if (lane == 0) mnorm[row] = s;
}

// ---------------- fused kNN GEMM + per-block candidate selection ----------------
// m97 structure: 128x128 tile, BK=64, 256 thr = 4 waves (2x2 of 64x64).
// Epilogue (NO lane-level pruning — round-4 bug): 4 nt-passes dump ALL raw
// fp32 scores to LDS; per-(row, 64-col half) reducer keeps top-4 of 64.
// Drop needs >=4 coarse-betters in one 64-col half: P ~ 1.2e-4 total — safe.
__global__ __launch_bounds__(256) void gemm_knn_kernel(
        const unsigned short* __restrict__ Qb,   // [4096][512] bf16
        const unsigned short* __restrict__ Mb,   // [NMEM][512] bf16
        const float* __restrict__ mnorm,
        uint2* __restrict__ cand_part) {         // [4096][ENT] (score bits, col)
    // stride 34 (== 2 mod 8 words): 8*quad bank offset -> 2-way (free) on
    // both dump writes and reducer reads [m136: 2-way conflict-free]
    __shared__ __align__(16) union {
        struct { unsigned short As[128 * 64]; unsigned short Bs[128 * 64]; } g; // 32 KB
        struct { float s[128][34]; unsigned i[128][34]; } p;                    // 34.8 KB
    } sh;
    const int tid  = threadIdx.x;
    const int wave = tid >> 6, lane = tid & 63;
    const int quad = lane >> 4, c16 = lane & 15;
    const int m0 = blockIdx.y * 128, n0 = blockIdx.x * 128;
    const int wm0 = (wave >> 1) * 64, wn0 = (wave & 1) * 64;
    const int half = wave & 1;
    const int srow = wave * 32 + (lane >> 3);
    const int schunk = lane & 7;

    f32x4 acc[4][4] = {};

    for (int kt = 0; kt < DD; kt += 64) {
        __syncthreads();
        #pragma unroll
        for (int i = 0; i < 4; ++i) {
            const unsigned short* ga = Qb + (size_t)(m0 + srow + i * 8) * DD + kt + schunk * 8;
            async_copy16(ga, &sh.g.As[(wave * 32 + i * 8) * 64]);
            const unsigned short* gb = Mb + (size_t)(n0 + srow + i * 8) * DD + kt + schunk * 8;
            async_copy16(gb, &sh.g.Bs[(wave * 32 + i * 8) * 64]);
        }
        __syncthreads();
        #pragma unroll
        for (int ks = 0; ks < 64; ks += 32) {
            bf16x8 af[4], bff[4];
            #pragma unroll
            for (int mt = 0; mt < 4; ++mt)
                af[mt] = *(const bf16x8*)&sh.g.As[(wm0 + mt * 16 + c16) * 64 + ks + quad * 8];
            #pragma unroll
            for (int nt = 0; nt < 4; ++nt)
                bff[nt] = *(const bf16x8*)&sh.g.Bs[(wn0 + nt * 16 + c16) * 64 + ks + quad * 8];
            #pragma unroll
            for (int mt = 0; mt < 4; ++mt)
                #pragma unroll
                for (int nt = 0; nt < 4; ++nt)
                    acc[mt][nt] = __builtin_amdgcn_mfma_f32_16x16x32_bf16(
                        af[mt], bff[nt], acc[mt][nt], 0, 0, 0);
        }
    }
    __syncthreads();   // all LDS reads done before aliasing As/Bs with p.s/p.i

    const int cbase = n0 + wn0 + c16;
    float mn[4];
    #pragma unroll
    for (int nt = 0; nt < 4; ++nt) mn[nt] = mnorm[cbase + nt * 16];

    // reducer identity: thread -> (row, 64-col half)
    const int rrow = tid >> 1, rhalf = tid & 1;
    float ts[4]; unsigned ti_[4];
    #pragma unroll
    for (int p = 0; p < 4; ++p) { ts[p] = FINF; ti_[p] = IMAX; }

    #pragma unroll
    for (int nt = 0; nt < 4; ++nt) {
        // dump: every lane writes its 16 raw scores for this nt slice
        // [C/D: col = lane&15, row = quad*4 + reg]
        #pragma unroll
        for (int mt = 0; mt < 4; ++mt)
            #pragma unroll
            for (int r = 0; r < 4; ++r) {
                int row_local = wm0 + mt * 16 + quad * 4 + r;
                sh.p.s[row_local][half * 16 + c16] = fmaf(-2.f, acc[mt][nt][r], mn[nt]);
                sh.p.i[row_local][half * 16 + c16] = (unsigned)(cbase + nt * 16);
            }
        __syncthreads();
        // accumulate top-4 over this slice's 16 entries
        #pragma unroll
        for (int k = 0; k < 16; ++k) {
            float s = sh.p.s[rrow][rhalf * 16 + k];
            unsigned j = sh.p.i[rrow][rhalf * 16 + k];
            bool cm[4];
            #pragma unroll
            for (int p = 0; p < 4; ++p) cm[p] = s < ts[p];
            #pragma unroll
            for (int p = 3; p > 0; --p) {
                float tns = cm[p] ? s : ts[p];  unsigned tni = cm[p] ? j : ti_[p];
                ts[p] = cm[p-1] ? ts[p-1] : tns;
                ti_[p] = cm[p-1] ? ti_[p-1] : tni;
            }
            ts[0] = cm[0] ? s : ts[0];
            ti_[0] = cm[0] ? j : ti_[0];
        }
        __syncthreads();   // before next slice overwrites
    }

    uint2* dst = cand_part + (size_t)(m0 + rrow) * ENT + blockIdx.x * 8 + rhalf * 4;
    #pragma unroll
    for (int p = 0; p < 4; ++p) dst[p] = make_uint2(__float_as_uint(ts[p]), ti_[p]);
}

// ---------------- merge: per row, 2048 entries -> top-16 candidates ----------------
// One wave per row (4 rows/block).
__global__ __launch_bounds__(256) void knn_merge_kernel(
        const uint2* __restrict__ cand_part,
        int* __restrict__ knn_cand) {            // [4096][NCF]
    const int row = blockIdx.x * 4 + (threadIdx.x >> 6);
    const int lane = threadIdx.x & 63;
    const uint2* p = cand_part + (size_t)row * ENT;

    float ts[LK]; int ti[LK];
    #pragma unroll
    for (int q = 0; q < LK; ++q) { ts[q] = FINF; ti[q] = IMAX; }
    #pragma unroll
    for (int i = 0; i < ENT / 64; ++i) {
        uint2 e = p[lane + 64 * i];              // lane-contiguous, coalesced
        float s = __uint_as_float(e.x);
        int j = (int)e.y;
        bool cm[LK];
        #pragma unroll
        for (int q = 0; q < LK; ++q) cm[q] = s < ts[q];
        #pragma unroll
        for (int q = LK - 1; q > 0; --q) {
            float tns = cm[q] ? s : ts[q];  int tni = cm[q] ? j : ti[q];
            ts[q] = cm[q-1] ? ts[q-1] : tns;
            ti[q] = cm[q-1] ? ti[q-1] : tni;
        }
        ts[0] = cm[0] ? s : ts[0];
        ti[0] = cm[0] ? j : ti[0];
    }

    // 16 rounds of wave argmin extraction (col idx unique per row -> exact winner)
    int ki = IMAX;
    #pragma unroll
    for (int r = 0; r < NCF; ++r) {
        float ms = ts[0]; int mi = ti[0];
        #pragma unroll
        for (int off = 1; off < 64; off <<= 1) {
            float os = __shfl_xor(ms, off, 64);
            int   oi = __shfl_xor(mi, off, 64);
            bool t = (os < ms) || (os == ms && oi < mi);
            ms = t ? os : ms; mi = t ? oi : mi;
        }
        bool win = (ti[0] == mi);
        #pragma unroll
        for (int q = 0; q < LK - 1; ++q) {
            ts[q] = win ? ts[q+1] : ts[q];
            ti[q] = win ? ti[q+1] : ti[q];
        }
        ts[LK-1] = win ? FINF : ts[LK-1];
        ti[LK-1] = win ? IMAX : ti[LK-1];
        if (lane == r) ki = mi;
    }
    if (lane < NCF) knn_cand[row * NCF + lane] = ki;
}

// ---------------- exact fp32 rescore of 16 candidates -> top-10 ----------------
__global__ __launch_bounds__(256) void rescore_kernel(
        const float* __restrict__ Q, const float* __restrict__ Mm,
        const float* __restrict__ mnorm, const int* __restrict__ cand,
        int* __restrict__ knn_idx) {
    const int row = blockIdx.x;
    const int wave = threadIdx.x >> 6, lane = threadIdx.x & 63;
    float4 q0 = *(const float4*)(Q + (size_t)row * DD + lane * 8);
    float4 q1 = *(const float4*)(Q + (size_t)row * DD + lane * 8 + 4);
    __shared__ float d2s[NCF];
    __shared__ int   ids[NCF];
    for (int c = wave; c < NCF; c += 4) {
        int j = cand[row * NCF + c];
        const float* mr = Mm + (size_t)j * DD;
        float4 m0 = *(const float4*)(mr + lane * 8);
        float4 m1 = *(const float4*)(mr + lane * 8 + 4);
        float dot = q0.x*m0.x + q0.y*m0.y + q0.z*m0.z + q0.w*m0.w
                  + q1.x*m1.x + q1.y*m1.y + q1.z*m1.z + q1.w*m1.w;
        #pragma unroll
        for (int off = 32; off; off >>= 1) dot += __shfl_xor(dot, off, 64);
        if (lane == 0) { d2s[c] = fmaf(-2.f, dot, mnorm[j]); ids[c] = j; }
    }
    __syncthreads();
    if (threadIdx.x == 0) {
        float ts[TOPN]; int ti[TOPN];
        #pragma unroll
        for (int p = 0; p < TOPN; ++p) { ts[p] = FINF; ti[p] = IMAX; }
        for (int c = 0; c < NCF; ++c) topk_insert<TOPN>(ts, ti, d2s[c], ids[c]);
        #pragma unroll
        for (int p = 0; p < TOPN; ++p) knn_idx[row * TOPN + p] = ti[p];
    }
}

// ---------------- unified bf16 MFMA GEMM (m97 structure) ----------------
template<int ACT, int HAS_BIAS, int OUT_BF16>
__global__ __launch_bounds__(256) void gemm_bf16_nt(
        const unsigned short* __restrict__ A,
        const unsigned short* __restrict__ B,
        const float* __restrict__ bias,
        void* __restrict__ Cout, int ldc) {
    __shared__ __align__(16) unsigned short As[128 * 64];
    __shared__ __align__(16) unsigned short Bs[128 * 64];
    const int tid  = threadIdx.x;
    const int wave = tid >> 6, lane = tid & 63;
    const int quad = lane >> 4, c16 = lane & 15;
    const int m0 = blockIdx.y * 128, n0 = blockIdx.x * 128;
    const int wm0 = (wave >> 1) * 64, wn0 = (wave & 1) * 64;
    const int srow = wave * 32 + (lane >> 3);
    const int schunk = lane & 7;

    f32x4 acc[4][4] = {};

    for (int kt = 0; kt < DD; kt += 64) {
        __syncthreads();
        #pragma unroll
        for (int i = 0; i < 4; ++i) {
            const unsigned short* ga = A + (size_t)(m0 + srow + i * 8) * DD + kt + schunk * 8;
            async_copy16(ga, &As[(wave * 32 + i * 8) * 64]);
            const unsigned short* gb = B + (size_t)(n0 + srow + i * 8) * DD + kt + schunk * 8;
            async_copy16(gb, &Bs[(wave * 32 + i * 8) * 64]);
        }
        __syncthreads();
        #pragma unroll
        for (int ks = 0; ks < 64; ks += 32) {
            bf16x8 af[4], bff[4];
            #pragma unroll
            for (int mt = 0; mt < 4; ++mt)
                af[mt] = *(const bf16x8*)&As[(wm0 + mt * 16 + c16) * 64 + ks + quad * 8];
            #pragma unroll
            for (int nt = 0; nt < 4; ++nt)
                bff[nt] = *(const bf16x8*)&Bs[(wn0 + nt * 16 + c16) * 64 + ks + quad * 8];
            #pragma unroll
            for (int mt = 0; mt < 4; ++mt)
                #pragma unroll
                for (int nt = 0; nt < 4; ++nt)
                    acc[mt][nt] = __builtin_amdgcn_mfma_f32_16x16x32_bf16(
                        af[mt], bff[nt], acc[mt][nt], 0, 0, 0);
        }
    }
    #pragma unroll
    for (int nt = 0; nt < 4; ++nt) {
        int ncol = n0 + wn0 + nt * 16 + c16;
        float bv = HAS_BIAS ? bias[ncol] : 0.f;
        #pragma unroll
        for (int mt = 0; mt < 4; ++mt) {
            size_t rbase = (size_t)(m0 + wm0 + mt * 16 + quad * 4) * ldc + ncol;
            #pragma unroll
            for (int r = 0; r < 4; ++r) {
                float v = acc[mt][nt][r] + bv;
                if (ACT == 1) v = v >= 0.f ? v : 0.01f * v;
                if (OUT_BF16) ((unsigned short*)Cout)[rbase + (size_t)r * ldc] = f2bf(v);
                else          ((float*)Cout)[rbase + (size_t)r * ldc] = v;
            }
        }
    }
}

// ---------------- attention: one block per query row, one wave per head ----------------
__global__ __launch_bounds__(512) void attn_kernel(
        const float* __restrict__ qh, const unsigned short* __restrict__ Kall,
        const unsigned short* __restrict__ Vall, const int* __restrict__ knn_idx,
        float* __restrict__ ctx) {
    const int b = blockIdx.x;
    const int h = threadIdx.x >> 6;
    const int l = threadIdx.x & 63;
    const int col = (h << 6) + l;
    int idxs[TOPN];
    #pragma unroll
    for (int n = 0; n < TOPN; ++n) idxs[n] = knn_idx[b * TOPN + n];
    const float q = qh[(size_t)b * DD + col];
    float sc[TOPN];
    #pragma unroll
    for (int n = 0; n < TOPN; ++n) {
        float p = q * bf2f(Kall[(size_t)idxs[n] * DD + col]);
        #pragma unroll
        for (int off = 32; off; off >>= 1) p += __shfl_xor(p, off, 64);
        sc[n] = p * 0.125f;
    }
    float mx = sc[0];
    #pragma unroll
    for (int n = 1; n < TOPN; ++n) mx = fmaxf(mx, sc[n]);
    float se = 0.f;
    #pragma unroll
    for (int n = 0; n < TOPN; ++n) { sc[n] = expf(sc[n] - mx); se += sc[n]; }
    const float inv = 1.f / se;
    float o = 0.f;
    #pragma unroll
    for (int n = 0; n < TOPN; ++n)
        o = fmaf(sc[n] * inv, bf2f(Vall[(size_t)idxs[n] * DD + col]), o);
    ctx[(size_t)b * DD + col] = o;
}

// ---------------- residual add + layernorm ----------------
__global__ __launch_bounds__(256) void add_ln_kernel(
        const float* __restrict__ X, const float* __restrict__ Y,
        const float* __restrict__ g, const float* __restrict__ be,
        float* __restrict__ out) {
    const int row = blockIdx.x;
    const int t = threadIdx.x;
    const size_t base = (size_t)row * DD;
    float v0 = X[base + t]       + Y[base + t];
    float v1 = X[base + 256 + t] + Y[base + 256 + t];
    float s = v0 + v1, sq = v0 * v0 + v1 * v1;
    #pragma unroll
    for (int off = 32; off; off >>= 1) { s += __shfl_xor(s, off, 64); sq += __shfl_xor(sq, off, 64); }
    __shared__ float rs[4], rq[4];
    const int w = t >> 6, l = t & 63;
    if (l == 0) { rs[w] = s; rq[w] = sq; }
    __syncthreads();
    float tot  = rs[0] + rs[1] + rs[2] + rs[3];
    float totq = rq[0] + rq[1] + rq[2] + rq[3];
    float mu = tot * (1.f / DD);
    float var = totq * (1.f / DD) - mu * mu;
    float rstd = rsqrtf(var + 1e-5f);
    out[base + t]       = (v0 - mu) * rstd * g[t]       + be[t];
    out[base + 256 + t] = (v1 - mu) * rstd * g[256 + t] + be[256 + t];
}

// ---------------- launch ----------------
extern "C" void kernel_launch(void* const* d_in, const int* in_sizes, int n_in,
                              void* d_out, int out_size, void* d_ws, size_t ws_size,
                              hipStream_t stream) {
    const float* visit = (const float*)d_in[0];
    const float* Epat  = (const float*)d_in[1];
    const float* Emed  = (const float*)d_in[2];
    const float* Wq = (const float*)d_in[3];
    const float* Wk = (const float*)d_in[4];
    const float* Wv = (const float*)d_in[5];
    const float* bq = (const float*)d_in[6];
    const float* bk = (const float*)d_in[7];
    const float* bv = (const float*)d_in[8];
    const float* Wo = (const float*)d_in[9];
    const float* bo = (const float*)d_in[10];
    const float* W1 = (const float*)d_in[11];
    const float* b1 = (const float*)d_in[12];
    const float* W2 = (const float*)d_in[13];
    const float* b2 = (const float*)d_in[14];
    const float* ln1g = (const float*)d_in[15];
    const float* ln1b = (const float*)d_in[16];
    const float* ln2g = (const float*)d_in[17];
    const float* ln2b = (const float*)d_in[18];
    float* out = (float*)d_out;

    // ---- workspace layout, ~174 MB peak (round-1 used 179 MB OK) ----
    char* base = (char*)d_ws;
    const size_t MB = 1u << 20;
    float* mnorm   = (float*)(base);                    // 128 KB
    int*   knn_cand= (int*)  (base + 1*MB);             // 256 KB
    int*   knn_idx = (int*)  (base + 2*MB);             // 160 KB
    float* qh      = (float*)(base + 3*MB);             // 8 MB
    float* attn_o  = qh;                                // alias: qh dead after attn
    float* ctx     = (float*)(base + 11*MB);            // 8 MB
    float* x1      = ctx;                               // alias: ctx dead after cast
    float* ff      = (float*)(base + 19*MB);            // 8 MB
    unsigned short* Qb    = (unsigned short*)(base + 27*MB);  // 4 MB (visit bf16)
    unsigned short* ctx_b = (unsigned short*)(base + 31*MB);  // 4 MB
    unsigned short* x1_b  = (unsigned short*)(base + 35*MB);  // 4 MB
    unsigned short* h1_b  = (unsigned short*)(base + 39*MB);  // 4 MB
    unsigned short* Wq_b  = (unsigned short*)(base + 43*MB);  // 6 x 512 KB
    unsigned short* Wk_b  = Wq_b + 262144;
    unsigned short* Wv_b  = Wk_b + 262144;
    unsigned short* Wo_b  = Wv_b + 262144;
    unsigned short* W1_b  = Wo_b + 262144;
    unsigned short* W2_b  = W1_b + 262144;
    unsigned short* Mb     = (unsigned short*)(base + 46*MB); // 32 MB (Epat bf16)
    unsigned short* Emed_b = (unsigned short*)(base + 78*MB); // 32 MB
    // K|V region (64 MB bf16), aliased by cand_part during the kNN phase
    unsigned short* Kall = (unsigned short*)(base + 110*MB);  // 32 MB
    unsigned short* Vall = Kall + (size_t)NMEM * DD;          // 32 MB
    uint2* cand_part = (uint2*)Kall;                          // 64 MB alias (kNN only)

    // ---- casts + norms ----
    mnorm_kernel<<<NMEM / 4, 256, 0, stream>>>(Epat, mnorm);
    cast_bf16_kernel<<<(BQ * DD) / 1024,   256, 0, stream>>>(visit, Qb);
    cast_bf16_kernel<<<(NMEM * DD) / 1024, 256, 0, stream>>>(Epat, Mb);
    cast_bf16_kernel<<<(NMEM * DD) / 1024, 256, 0, stream>>>(Emed, Emed_b);
    cast_bf16_kernel<<<256, 256, 0, stream>>>(Wq, Wq_b);
    cast_bf16_kernel<<<256, 256, 0, stream>>>(Wk, Wk_b);
    cast_bf16_kernel<<<256, 256, 0, stream>>>(Wv, Wv_b);
    cast_bf16_kernel<<<256, 256, 0, stream>>>(Wo, Wo_b);
    cast_bf16_kernel<<<256, 256, 0, stream>>>(W1, W1_b);
    cast_bf16_kernel<<<256, 256, 0, stream>>>(W2, W2_b);

    // ---- kNN: fused MFMA scores + selection -> merge -> exact fp32 rescore ----
    gemm_knn_kernel<<<dim3(CB, BQ / 128), 256, 0, stream>>>(Qb, Mb, mnorm, cand_part);
    knn_merge_kernel<<<BQ / 4, 256, 0, stream>>>(cand_part, knn_cand);
    rescore_kernel<<<BQ, 256, 0, stream>>>(visit, Epat, mnorm, knn_cand, knn_idx);

    // ---- projections (all bf16 MFMA); Kall write overwrites cand_part (dead) ----
    gemm_bf16_nt<0,1,1><<<dim3(4, NMEM / 128), 256, 0, stream>>>(Mb,     Wk_b, bk, Kall, DD);
    gemm_bf16_nt<0,1,1><<<dim3(4, NMEM / 128), 256, 0, stream>>>(Emed_b, Wv_b, bv, Vall, DD);
    gemm_bf16_nt<0,1,0><<<dim3(4, BQ / 128),   256, 0, stream>>>(Qb,     Wq_b, bq, qh,   DD);

    attn_kernel<<<BQ, 512, 0, stream>>>(qh, Kall, Vall, knn_idx, ctx);
    cast_bf16_kernel<<<(BQ * DD) / 1024, 256, 0, stream>>>(ctx, ctx_b);

    gemm_bf16_nt<0,1,0><<<dim3(4, BQ / 128), 256, 0, stream>>>(ctx_b, Wo_b, bo, attn_o, DD);
    add_ln_kernel<<<BQ, 256, 0, stream>>>(visit, attn_o, ln1g, ln1b, x1);
    cast_bf16_kernel<<<(BQ * DD) / 1024, 256, 0, stream>>>(x1, x1_b);
    gemm_bf16_nt<1,1,1><<<dim3(4, BQ / 128), 256, 0, stream>>>(x1_b, W1_b, b1, h1_b, DD);
    gemm_bf16_nt<0,1,0><<<dim3(4, BQ / 128), 256, 0, stream>>>(h1_b, W2_b, b2, ff,   DD);
    add_ln_kernel<<<BQ, 256, 0, stream>>>(x1, ff, ln2g, ln2b, out);
}

// Round 6
// 651.187 us; speedup vs baseline: 13.5791x; 1.1708x over previous
//
#include <hip/hip_runtime.h>
#include <math.h>

#define BQ 4096
#define NMEM 32768
#define DD 512
#define TOPN 10
#define CB 256                   /* 128-col blocks over NMEM */
#define ENT 2048                 /* candidate entries per row = CB*8 */
#define NCF 16                   /* final candidates per row */
#define LK 6                     /* per-lane top-K in merge */
#define SSTR 132                 /* LDS score stride (words): %4==0 (b128 align), uniform banks */
#define FINF 3.402823466e+38f
#define IMAX 0x7fffffff

typedef __attribute__((ext_vector_type(8))) short    bf16x8;
typedef __attribute__((ext_vector_type(4))) float    f32x4;

// ---------------- helpers ----------------
__device__ __forceinline__ unsigned short f2bf(float x) {
    unsigned int u = __float_as_uint(x);
    u += 0x7fffu + ((u >> 16) & 1u);          // round-to-nearest-even
    return (unsigned short)(u >> 16);
}
__device__ __forceinline__ void async_copy16(const void* gp, void* lp) {
    __builtin_amdgcn_global_load_lds(
        (const __attribute__((address_space(1))) void*)gp,
        (__attribute__((address_space(3))) void*)lp, 16, 0, 0);
}
__device__ __forceinline__ bool lt_si(float s, int j, float s2, int j2) {
    return (s < s2) || (s == s2 && j < j2);   // matches top_k tie-break
}
template<int KN>
__device__ __forceinline__ void topk_insert(float (&ts)[KN], int (&ti)[KN], float s, int j) {
    if (!lt_si(s, j, ts[KN-1], ti[KN-1])) return;
    #pragma unroll
    for (int p = KN-1; p > 0; --p) {
        if (lt_si(s, j, ts[p-1], ti[p-1])) { ts[p] = ts[p-1]; ti[p] = ti[p-1]; }
        else { ts[p] = s; ti[p] = j; return; }
    }
    ts[0] = s; ti[0] = j;
}

// ---------------- casts ----------------
__global__ __launch_bounds__(256) void cast_bf16_kernel(const float* __restrict__ in,
                                                        unsigned short* __restrict__ out) {
    int i = (blockIdx.x * 256 + threadIdx.x) * 4;
    float4 v = *(const float4*)(in + i);
    ushort4 o;
    o.x = f2bf(v.x); o.y = f2bf(v.y); o.z = f2bf(v.z); o.w = f2bf(v.w);
    *(ushort4*)(out + i) = o;
}

struct W6 { const float* in[6]; unsigned short* out[6]; };
__global__ __launch_bounds__(256) void cast_w6_kernel(W6 p) {
    const float* in = p.in[blockIdx.y];
    unsigned short* out = p.out[blockIdx.y];
    int i = (blockIdx.x * 256 + threadIdx.x) * 4;
    float4 v = *(const float4*)(in + i);
    ushort4 o;
    o.x = f2bf(v.x); o.y = f2bf(v.y); o.z = f2bf(v.z); o.w = f2bf(v.w);
    *(ushort4*)(out + i) = o;
}

// ---------------- fused fp32->bf16 cast + ||row||^2 (one pass over Epat) ----------------
__global__ __launch_bounds__(256) void cast_norm_kernel(const float* __restrict__ in,
                                                        unsigned short* __restrict__ out,
                                                        float* __restrict__ mnorm) {
    int row = blockIdx.x * 4 + (threadIdx.x >> 6);
    int lane = threadIdx.x & 63;
    const float* r = in + (size_t)row * DD + lane * 8;
    float4 a = *(const float4*)r;
    float4 b = *(const float4*)(r + 4);
    ushort4 oa, ob;
    oa.x = f2bf(a.x); oa.y = f2bf(a.y); oa.z = f2bf(a.z); oa.w = f2bf(a.w);
    ob.x = f2bf(b.x); ob.y = f2bf(b.y); ob.z = f2bf(b.z); ob.w = f2bf(b.w);
    unsigned short* op = out + (size_t)row * DD + lane * 8;
    *(ushort4*)op = oa; *(ushort4*)(op + 4) = ob;
    float s = a.x*a.x + a.y*a.y + a.z*a.z + a.w*a.w
            + b.x*b.x + b.y*b.y + b.z*b.z + b.w*b.w;
    #pragma unroll
    for (int off = 32; off; off >>= 1) s += __shfl_xor(s, off, 64);
    if (lane == 0) mnorm[row] = s;
}

// ---------------- fused kNN GEMM + per-block candidate selection ----------------
// m97 structure main loop. Epilogue: scores packed to monotone-uint
// (score_bits & ~127) | local_col, dumped via ds_write_b128 (4 C-rows are
// register-contiguous); per-(row, 64-col half) reducer keeps top-4 of 64 via
// 8-op min/max sorted insert. No index array, no lane-level pruning
// (round-4 lesson): drop needs >=4 coarse-betters in one 64-col half
// (P ~ 1.2e-4 total). Score truncation (7 mantissa bits ~ <=0.03) << bf16
// coarse noise ~0.1; final top-10 is exact fp32 rescore.
__global__ __launch_bounds__(256) void gemm_knn_kernel(
        const unsigned short* __restrict__ Qb,   // [4096][512] bf16
        const unsigned short* __restrict__ Mb,   // [NMEM][512] bf16
        const float* __restrict__ mnorm,
        uint2* __restrict__ cand_part) {         // [4096][ENT] (packed key, col)
    __shared__ __align__(16) union {
        struct { unsigned short As[128 * 64]; unsigned short Bs[128 * 64]; } g; // 32 KB
        unsigned S[64 * SSTR];                                                  // 33 KB
    } sh;
    const int tid  = threadIdx.x;
    const int wave = tid >> 6, lane = tid & 63;
    const int quad = lane >> 4, c16 = lane & 15;
    const int m0 = blockIdx.y * 128, n0 = blockIdx.x * 128;
    const int wm0 = (wave >> 1) * 64, wn0 = (wave & 1) * 64;
    const int half = wave & 1;
    const int srow = wave * 32 + (lane >> 3);
    const int schunk = lane & 7;

    f32x4 acc[4][4] = {};

    for (int kt = 0; kt < DD; kt += 64) {
        __syncthreads();
        #pragma unroll
        for (int i = 0; i < 4; ++i) {
            const unsigned short* ga = Qb + (size_t)(m0 + srow + i * 8) * DD + kt + schunk * 8;
            async_copy16(ga, &sh.g.As[(wave * 32 + i * 8) * 64]);
            const unsigned short* gb = Mb + (size_t)(n0 + srow + i * 8) * DD + kt + schunk * 8;
            async_copy16(gb, &sh.g.Bs[(wave * 32 + i * 8) * 64]);
        }
        __syncthreads();
        #pragma unroll
        for (int ks = 0; ks < 64; ks += 32) {
            bf16x8 af[4], bff[4];
            #pragma unroll
            for (int mt = 0; mt < 4; ++mt)
                af[mt] = *(const bf16x8*)&sh.g.As[(wm0 + mt * 16 + c16) * 64 + ks + quad * 8];
            #pragma unroll
            for (int nt = 0; nt < 4; ++nt)
                bff[nt] = *(const bf16x8*)&sh.g.Bs[(wn0 + nt * 16 + c16) * 64 + ks + quad * 8];
            #pragma unroll
            for (int mt = 0; mt < 4; ++mt)
                #pragma unroll
                for (int nt = 0; nt < 4; ++nt)
                    acc[mt][nt] = __builtin_amdgcn_mfma_f32_16x16x32_bf16(
                        af[mt], bff[nt], acc[mt][nt], 0, 0, 0);
        }
    }

    const int cbase = n0 + wn0 + c16;
    float mn[4];
    #pragma unroll
    for (int nt = 0; nt < 4; ++nt) mn[nt] = mnorm[cbase + nt * 16];

    const int rrow = tid >> 1, rhalf = tid & 1;   // reducer identity
    unsigned q4[4] = {0xFFFFFFFFu, 0xFFFFFFFFu, 0xFFFFFFFFu, 0xFFFFFFFFu};

    __syncthreads();   // main-loop LDS reads done before aliasing As/Bs
    #pragma unroll
    for (int p = 0; p < 2; ++p) {
        // dump: nt = 2p, 2p+1. [C/D: col=lane&15, row=quad*4+reg]
        #pragma unroll
        for (int mt = 0; mt < 4; ++mt)
            #pragma unroll
            for (int b = 0; b < 2; ++b) {
                const int nt = 2 * p + b;
                const int lcol = half * 64 + nt * 16 + c16;   // 7-bit local col
                uint4 w;
                #pragma unroll
                for (int r = 0; r < 4; ++r) {
                    float s = fmaf(-2.f, acc[mt][nt][r], mn[nt]);
                    unsigned u = __float_as_uint(s);
                    u ^= (unsigned)((int)u >> 31) | 0x80000000u;  // monotone map
                    (&w.x)[r] = (u & 0xFFFFFF80u) | (unsigned)lcol;
                }
                const int slot = half * 32 + b * 16 + c16;
                *(uint4*)&sh.S[slot * SSTR + wm0 + mt * 16 + quad * 4] = w;
            }
        __syncthreads();
        // reduce: 32 cols of this pass for (rrow, rhalf)
        #pragma unroll
        for (int m = 0; m < 32; ++m) {
            unsigned nv = sh.S[(rhalf * 32 + m) * SSTR + rrow];
            #pragma unroll
            for (int i = 0; i < 4; ++i) {
                unsigned lo = min(q4[i], nv);
                nv = max(q4[i], nv);
                q4[i] = lo;
            }
        }
        __syncthreads();   // before next pass overwrites
    }

    uint2* dst = cand_part + (size_t)(m0 + rrow) * ENT + blockIdx.x * 8 + rhalf * 4;
    #pragma unroll
    for (int i = 0; i < 4; ++i)
        dst[i] = make_uint2(q4[i], (unsigned)(n0 + (int)(q4[i] & 127u)));
}

// ---------------- merge: per row, 2048 packed entries -> top-16 candidates ----------------
// One wave per row (4 rows/block). Keys are monotone-mapped uints.
__global__ __launch_bounds__(256) void knn_merge_kernel(
        const uint2* __restrict__ cand_part,
        int* __restrict__ knn_cand) {            // [4096][NCF]
    const int row = blockIdx.x * 4 + (threadIdx.x >> 6);
    const int lane = threadIdx.x & 63;
    const uint2* p = cand_part + (size_t)row * ENT;

    unsigned ks[LK]; int ti[LK];
    #pragma unroll
    for (int q = 0; q < LK; ++q) { ks[q] = 0xFFFFFFFFu; ti[q] = IMAX; }
    #pragma unroll
    for (int i = 0; i < ENT / 64; ++i) {
        uint2 e = p[lane + 64 * i];              // lane-contiguous, coalesced
        unsigned k = e.x;
        int j = (int)e.y;
        bool cm[LK];
        #pragma unroll
        for (int q = 0; q < LK; ++q) cm[q] = k < ks[q];
        #pragma unroll
        for (int q = LK - 1; q > 0; --q) {
            unsigned tns = cm[q] ? k : ks[q];  int tni = cm[q] ? j : ti[q];
            ks[q] = cm[q-1] ? ks[q-1] : tns;
            ti[q] = cm[q-1] ? ti[q-1] : tni;
        }
        ks[0] = cm[0] ? k : ks[0];
        ti[0] = cm[0] ? j : ti[0];
    }

    // 16 rounds of wave argmin extraction (global col unique per row -> exact winner)
    int ki = IMAX;
    #pragma unroll
    for (int r = 0; r < NCF; ++r) {
        unsigned mk = ks[0]; int mi = ti[0];
        #pragma unroll
        for (int off = 1; off < 64; off <<= 1) {
            unsigned ok = (unsigned)__shfl_xor((int)mk, off, 64);
            int      oi = __shfl_xor(mi, off, 64);
            bool t = (ok < mk) || (ok == mk && oi < mi);
            mk = t ? ok : mk; mi = t ? oi : mi;
        }
        bool win = (ti[0] == mi);
        #pragma unroll
        for (int q = 0; q < LK - 1; ++q) {
            ks[q] = win ? ks[q+1] : ks[q];
            ti[q] = win ? ti[q+1] : ti[q];
        }
        ks[LK-1] = win ? 0xFFFFFFFFu : ks[LK-1];
        ti[LK-1] = win ? IMAX : ti[LK-1];
        if (lane == r) ki = mi;
    }
    if (lane < NCF) knn_cand[row * NCF + lane] = ki;
}

// ---------------- exact fp32 rescore of 16 candidates -> top-10 ----------------
__global__ __launch_bounds__(256) void rescore_kernel(
        const float* __restrict__ Q, const float* __restrict__ Mm,
        const float* __restrict__ mnorm, const int* __restrict__ cand,
        int* __restrict__ knn_idx) {
    const int row = blockIdx.x;
    const int wave = threadIdx.x >> 6, lane = threadIdx.x & 63;
    float4 q0 = *(const float4*)(Q + (size_t)row * DD + lane * 8);
    float4 q1 = *(const float4*)(Q + (size_t)row * DD + lane * 8 + 4);
    __shared__ float d2s[NCF];
    __shared__ int   ids[NCF];
    for (int c = wave; c < NCF; c += 4) {
        int j = cand[row * NCF + c];
        const float* mr = Mm + (size_t)j * DD;
        float4 m0 = *(const float4*)(mr + lane * 8);
        float4 m1 = *(const float4*)(mr + lane * 8 + 4);
        float dot = q0.x*m0.x + q0.y*m0.y + q0.z*m0.z + q0.w*m0.w
                  + q1.x*m1.x + q1.y*m1.y + q1.z*m1.z + q1.w*m1.w;
        #pragma unroll
        for (int off = 32; off; off >>= 1) dot += __shfl_xor(dot, off, 64);
        if (lane == 0) { d2s[c] = fmaf(-2.f, dot, mnorm[j]); ids[c] = j; }
    }
    __syncthreads();
    if (threadIdx.x == 0) {
        float ts[TOPN]; int ti[TOPN];
        #pragma unroll
        for (int p = 0; p < TOPN; ++p) { ts[p] = FINF; ti[p] = IMAX; }
        for (int c = 0; c < NCF; ++c) topk_insert<TOPN>(ts, ti, d2s[c], ids[c]);
        #pragma unroll
        for (int p = 0; p < TOPN; ++p) knn_idx[row * TOPN + p] = ti[p];
    }
}

// ---------------- unified bf16 MFMA GEMM (m97 structure) ----------------
template<int ACT, int HAS_BIAS, int OUT_BF16>
__global__ __launch_bounds__(256) void gemm_bf16_nt(
        const unsigned short* __restrict__ A,
        const unsigned short* __restrict__ B,
        const float* __restrict__ bias,
        void* __restrict__ Cout, int ldc) {
    __shared__ __align__(16) unsigned short As[128 * 64];
    __shared__ __align__(16) unsigned short Bs[128 * 64];
    const int tid  = threadIdx.x;
    const int wave = tid >> 6, lane = tid & 63;
    const int quad = lane >> 4, c16 = lane & 15;
    const int m0 = blockIdx.y * 128, n0 = blockIdx.x * 128;
    const int wm0 = (wave >> 1) * 64, wn0 = (wave & 1) * 64;
    const int srow = wave * 32 + (lane >> 3);
    const int schunk = lane & 7;

    f32x4 acc[4][4] = {};

    for (int kt = 0; kt < DD; kt += 64) {
        __syncthreads();
        #pragma unroll
        for (int i = 0; i < 4; ++i) {
            const unsigned short* ga = A + (size_t)(m0 + srow + i * 8) * DD + kt + schunk * 8;
            async_copy16(ga, &As[(wave * 32 + i * 8) * 64]);
            const unsigned short* gb = B + (size_t)(n0 + srow + i * 8) * DD + kt + schunk * 8;
            async_copy16(gb, &Bs[(wave * 32 + i * 8) * 64]);
        }
        __syncthreads();
        #pragma unroll
        for (int ks = 0; ks < 64; ks += 32) {
            bf16x8 af[4], bff[4];
            #pragma unroll
            for (int mt = 0; mt < 4; ++mt)
                af[mt] = *(const bf16x8*)&As[(wm0 + mt * 16 + c16) * 64 + ks + quad * 8];
            #pragma unroll
            for (int nt = 0; nt < 4; ++nt)
                bff[nt] = *(const bf16x8*)&Bs[(wn0 + nt * 16 + c16) * 64 + ks + quad * 8];
            #pragma unroll
            for (int mt = 0; mt < 4; ++mt)
                #pragma unroll
                for (int nt = 0; nt < 4; ++nt)
                    acc[mt][nt] = __builtin_amdgcn_mfma_f32_16x16x32_bf16(
                        af[mt], bff[nt], acc[mt][nt], 0, 0, 0);
        }
    }
    #pragma unroll
    for (int nt = 0; nt < 4; ++nt) {
        int ncol = n0 + wn0 + nt * 16 + c16;
        float bv = HAS_BIAS ? bias[ncol] : 0.f;
        #pragma unroll
        for (int mt = 0; mt < 4; ++mt) {
            size_t rbase = (size_t)(m0 + wm0 + mt * 16 + quad * 4) * ldc + ncol;
            #pragma unroll
            for (int r = 0; r < 4; ++r) {
                float v = acc[mt][nt][r] + bv;
                if (ACT == 1) v = v >= 0.f ? v : 0.01f * v;
                if (OUT_BF16) ((unsigned short*)Cout)[rbase + (size_t)r * ldc] = f2bf(v);
                else          ((float*)Cout)[rbase + (size_t)r * ldc] = v;
            }
        }
    }
}

// ---------------- attention: one block per query row, one wave per head ----------------
// Writes bf16 ctx directly (feeds the Wo bf16 GEMM; same numerics as cast).
__global__ __launch_bounds__(512) void attn_kernel(
        const float* __restrict__ qh, const unsigned short* __restrict__ Kall,
        const unsigned short* __restrict__ Vall, const int* __restrict__ knn_idx,
        unsigned short* __restrict__ ctx_b) {
    const int b = blockIdx.x;
    const int h = threadIdx.x >> 6;
    const int l = threadIdx.x & 63;
    const int col = (h << 6) + l;
    int idxs[TOPN];
    #pragma unroll
    for (int n = 0; n < TOPN; ++n) idxs[n] = knn_idx[b * TOPN + n];
    const float q = qh[(size_t)b * DD + col];
    float sc[TOPN];
    #pragma unroll
    for (int n = 0; n < TOPN; ++n) {
        float p = q * __uint_as_float((unsigned)Kall[(size_t)idxs[n] * DD + col] << 16);
        #pragma unroll
        for (int off = 32; off; off >>= 1) p += __shfl_xor(p, off, 64);
        sc[n] = p * 0.125f;
    }
    float mx = sc[0];
    #pragma unroll
    for (int n = 1; n < TOPN; ++n) mx = fmaxf(mx, sc[n]);
    float se = 0.f;
    #pragma unroll
    for (int n = 0; n < TOPN; ++n) { sc[n] = expf(sc[n] - mx); se += sc[n]; }
    const float inv = 1.f / se;
    float o = 0.f;
    #pragma unroll
    for (int n = 0; n < TOPN; ++n)
        o = fmaf(sc[n] * inv,
                 __uint_as_float((unsigned)Vall[(size_t)idxs[n] * DD + col] << 16), o);
    ctx_b[(size_t)b * DD + col] = f2bf(o);
}

// ---------------- residual add + layernorm (optional bf16 secondary output) ----------------
template<int EMIT_BF16>
__global__ __launch_bounds__(256) void add_ln_kernel(
        const float* __restrict__ X, const float* __restrict__ Y,
        const float* __restrict__ g, const float* __restrict__ be,
        float* __restrict__ out, unsigned short* __restrict__ out_b) {
    const int row = blockIdx.x;
    const int t = threadIdx.x;
    const size_t base = (size_t)row * DD;
    float v0 = X[base + t]       + Y[base + t];
    float v1 = X[base + 256 + t] + Y[base + 256 + t];
    float s = v0 + v1, sq = v0 * v0 + v1 * v1;
    #pragma unroll
    for (int off = 32; off; off >>= 1) { s += __shfl_xor(s, off, 64); sq += __shfl_xor(sq, off, 64); }
    __shared__ float rs[4], rq[4];
    const int w = t >> 6, l = t & 63;
    if (l == 0) { rs[w] = s; rq[w] = sq; }
    __syncthreads();
    float tot  = rs[0] + rs[1] + rs[2] + rs[3];
    float totq = rq[0] + rq[1] + rq[2] + rq[3];
    float mu = tot * (1.f / DD);
    float var = totq * (1.f / DD) - mu * mu;
    float rstd = rsqrtf(var + 1e-5f);
    float o0 = (v0 - mu) * rstd * g[t]       + be[t];
    float o1 = (v1 - mu) * rstd * g[256 + t] + be[256 + t];
    out[base + t] = o0;
    out[base + 256 + t] = o1;
    if (EMIT_BF16) {
        out_b[base + t] = f2bf(o0);
        out_b[base + 256 + t] = f2bf(o1);
    }
}

// ---------------- launch ----------------
extern "C" void kernel_launch(void* const* d_in, const int* in_sizes, int n_in,
                              void* d_out, int out_size, void* d_ws, size_t ws_size,
                              hipStream_t stream) {
    const float* visit = (const float*)d_in[0];
    const float* Epat  = (const float*)d_in[1];
    const float* Emed  = (const float*)d_in[2];
    const float* Wq = (const float*)d_in[3];
    const float* Wk = (const float*)d_in[4];
    const float* Wv = (const float*)d_in[5];
    const float* bq = (const float*)d_in[6];
    const float* bk = (const float*)d_in[7];
    const float* bv = (const float*)d_in[8];
    const float* Wo = (const float*)d_in[9];
    const float* bo = (const float*)d_in[10];
    const float* W1 = (const float*)d_in[11];
    const float* b1 = (const float*)d_in[12];
    const float* W2 = (const float*)d_in[13];
    const float* b2 = (const float*)d_in[14];
    const float* ln1g = (const float*)d_in[15];
    const float* ln1b = (const float*)d_in[16];
    const float* ln2g = (const float*)d_in[17];
    const float* ln2b = (const float*)d_in[18];
    float* out = (float*)d_out;

    // ---- workspace layout, ~174 MB peak ----
    char* base = (char*)d_ws;
    const size_t MB = 1u << 20;
    float* mnorm   = (float*)(base);                    // 128 KB
    int*   knn_cand= (int*)  (base + 1*MB);             // 256 KB
    int*   knn_idx = (int*)  (base + 2*MB);             // 160 KB
    float* qh      = (float*)(base + 3*MB);             // 8 MB
    float* attn_o  = qh;                                // alias: qh dead after attn
    float* x1      = (float*)(base + 11*MB);            // 8 MB
    float* ff      = (float*)(base + 19*MB);            // 8 MB
    unsigned short* Qb    = (unsigned short*)(base + 27*MB);  // 4 MB (visit bf16)
    unsigned short* ctx_b = (unsigned short*)(base + 31*MB);  // 4 MB
    unsigned short* x1_b  = (unsigned short*)(base + 35*MB);  // 4 MB
    unsigned short* h1_b  = (unsigned short*)(base + 39*MB);  // 4 MB
    unsigned short* Wq_b  = (unsigned short*)(base + 43*MB);  // 6 x 512 KB
    unsigned short* Wk_b  = Wq_b + 262144;
    unsigned short* Wv_b  = Wk_b + 262144;
    unsigned short* Wo_b  = Wv_b + 262144;
    unsigned short* W1_b  = Wo_b + 262144;
    unsigned short* W2_b  = W1_b + 262144;
    unsigned short* Mb     = (unsigned short*)(base + 46*MB); // 32 MB (Epat bf16)
    unsigned short* Emed_b = (unsigned short*)(base + 78*MB); // 32 MB
    // K|V region (64 MB bf16), aliased by cand_part during the kNN phase
    unsigned short* Kall = (unsigned short*)(base + 110*MB);  // 32 MB
    unsigned short* Vall = Kall + (size_t)NMEM * DD;          // 32 MB
    uint2* cand_part = (uint2*)Kall;                          // 64 MB alias (kNN only)

    // ---- casts + norms (Epat cast fused with mnorm; 6 weights in 1 dispatch) ----
    cast_norm_kernel<<<NMEM / 4, 256, 0, stream>>>(Epat, Mb, mnorm);
    cast_bf16_kernel<<<(BQ * DD) / 1024,   256, 0, stream>>>(visit, Qb);
    cast_bf16_kernel<<<(NMEM * DD) / 1024, 256, 0, stream>>>(Emed, Emed_b);
    W6 w6;
    w6.in[0] = Wq; w6.in[1] = Wk; w6.in[2] = Wv; w6.in[3] = Wo; w6.in[4] = W1; w6.in[5] = W2;
    w6.out[0] = Wq_b; w6.out[1] = Wk_b; w6.out[2] = Wv_b; w6.out[3] = Wo_b; w6.out[4] = W1_b; w6.out[5] = W2_b;
    cast_w6_kernel<<<dim3(256, 6), 256, 0, stream>>>(w6);

    // ---- kNN: fused MFMA scores + selection -> merge -> exact fp32 rescore ----
    gemm_knn_kernel<<<dim3(CB, BQ / 128), 256, 0, stream>>>(Qb, Mb, mnorm, cand_part);
    knn_merge_kernel<<<BQ / 4, 256, 0, stream>>>(cand_part, knn_cand);
    rescore_kernel<<<BQ, 256, 0, stream>>>(visit, Epat, mnorm, knn_cand, knn_idx);

    // ---- projections (all bf16 MFMA); Kall write overwrites cand_part (dead) ----
    gemm_bf16_nt<0,1,1><<<dim3(4, NMEM / 128), 256, 0, stream>>>(Mb,     Wk_b, bk, Kall, DD);
    gemm_bf16_nt<0,1,1><<<dim3(4, NMEM / 128), 256, 0, stream>>>(Emed_b, Wv_b, bv, Vall, DD);
    gemm_bf16_nt<0,1,0><<<dim3(4, BQ / 128),   256, 0, stream>>>(Qb,     Wq_b, bq, qh,   DD);

    attn_kernel<<<BQ, 512, 0, stream>>>(qh, Kall, Vall, knn_idx, ctx_b);

    gemm_bf16_nt<0,1,0><<<dim3(4, BQ / 128), 256, 0, stream>>>(ctx_b, Wo_b, bo, attn_o, DD);
    add_ln_kernel<1><<<BQ, 256, 0, stream>>>(visit, attn_o, ln1g, ln1b, x1, x1_b);
    gemm_bf16_nt<1,1,1><<<dim3(4, BQ / 128), 256, 0, stream>>>(x1_b, W1_b, b1, h1_b, DD);
    gemm_bf16_nt<0,1,0><<<dim3(4, BQ / 128), 256, 0, stream>>>(h1_b, W2_b, b2, ff,   DD);
    add_ln_kernel<0><<<BQ, 256, 0, stream>>>(x1, ff, ln2g, ln2b, out, nullptr);
}